// Round 2
// baseline (2453.671 us; speedup 1.0000x reference)
//
#include <hip/hip_runtime.h>
#include <math.h>

#define E_DIM  1024
#define H_DIM  16
#define D_DIM  64
#define T_SEQ  1024
#define B_SZ   4
#define E3     3072
#define R_RANK 4

// ---------------- weight factorization ----------------
// out[a][b] = W[a][b] * rm[idx][a] * sm[idx][b] + sum_k r[idx][k][a] * s[idx][k][b]
__global__ void factorize_kernel(const float* __restrict__ W,
                                 const float* __restrict__ rm,
                                 const float* __restrict__ sm,
                                 const float* __restrict__ r,
                                 const float* __restrict__ s,
                                 const int* __restrict__ idxp,
                                 float* __restrict__ out,
                                 int A, int Bc) {
  int idx = idxp[0];
  long long i = (long long)blockIdx.x * blockDim.x + threadIdx.x;
  long long total = (long long)A * Bc;
  if (i >= total) return;
  int a = (int)(i / Bc);
  int b = (int)(i % Bc);
  float acc = W[i] * rm[(long long)idx * A + a] * sm[(long long)idx * Bc + b];
#pragma unroll
  for (int k = 0; k < R_RANK; ++k) {
    acc += r[((long long)idx * R_RANK + k) * A + a] *
           s[((long long)idx * R_RANK + k) * Bc + b];
  }
  out[i] = acc;
}

// ---------------- GEMM: C[M,N] = A[M,K] * B[N,K]^T + bias[N] ----------------
// 64x64 tile, K-tile 16, 256 threads, 4x4 per thread. All dims multiples of 64.
__global__ __launch_bounds__(256) void gemm_abt_kernel(
    const float* __restrict__ A, const float* __restrict__ Bm,
    const float* __restrict__ bias, float* __restrict__ C,
    int M, int N, int K) {
  __shared__ float As[16][68];
  __shared__ float Bs[16][68];
  int tid = threadIdx.x;
  int tx = tid & 15, ty = tid >> 4;
  int m0 = blockIdx.y * 64, n0 = blockIdx.x * 64;
  int lrow = tid >> 2;          // 0..63
  int lk = (tid & 3) << 2;      // 0,4,8,12
  const float* Ag = A + (long long)(m0 + lrow) * K + lk;
  const float* Bg = Bm + (long long)(n0 + lrow) * K + lk;
  float acc[4][4] = {};
  for (int k0 = 0; k0 < K; k0 += 16) {
    float4 av = *(const float4*)(Ag + k0);
    float4 bv = *(const float4*)(Bg + k0);
    __syncthreads();
    As[lk + 0][lrow] = av.x; As[lk + 1][lrow] = av.y;
    As[lk + 2][lrow] = av.z; As[lk + 3][lrow] = av.w;
    Bs[lk + 0][lrow] = bv.x; Bs[lk + 1][lrow] = bv.y;
    Bs[lk + 2][lrow] = bv.z; Bs[lk + 3][lrow] = bv.w;
    __syncthreads();
#pragma unroll
    for (int kk = 0; kk < 16; ++kk) {
      float4 a4 = *(const float4*)&As[kk][ty << 2];
      float4 b4 = *(const float4*)&Bs[kk][tx << 2];
      float aa[4] = {a4.x, a4.y, a4.z, a4.w};
      float bb[4] = {b4.x, b4.y, b4.z, b4.w};
#pragma unroll
      for (int i2 = 0; i2 < 4; ++i2)
#pragma unroll
        for (int j2 = 0; j2 < 4; ++j2)
          acc[i2][j2] = fmaf(aa[i2], bb[j2], acc[i2][j2]);
    }
  }
#pragma unroll
  for (int i2 = 0; i2 < 4; ++i2) {
    int m = m0 + (ty << 2) + i2;
    int n = n0 + (tx << 2);
    float4 o;
    o.x = acc[i2][0] + bias[n + 0];
    o.y = acc[i2][1] + bias[n + 1];
    o.z = acc[i2][2] + bias[n + 2];
    o.w = acc[i2][3] + bias[n + 3];
    *(float4*)&C[(long long)m * N + n] = o;
  }
}

// ---------------- fused rel-shift attention ----------------
// Grid: (T/16, B*H). Block 256 = 4 waves; each wave owns 4 query rows.
// Online softmax over s-tiles of 64. rel_shift handled analytically:
//   s <= t   : BD = qr[t]   . r[1023+s-t]
//   s == t+1 : BD = 0
//   s >= t+2 : BD = qr[t+1] . r[s-t-2]
// Unified LDS window: ib = 15 + lane - tl indexes an 80-row slice of r.
__global__ __launch_bounds__(256) void attn_kernel(
    const float* __restrict__ qkv, const float* __restrict__ rbuf,
    const float* __restrict__ rwb, const float* __restrict__ rrb,
    float* __restrict__ outb) {
  __shared__ float qw[16][64];   // q + r_w_bias (broadcast reads)
  __shared__ float qr[17][64];   // q + r_r_bias (rows t0..t0+16)
  __shared__ float Ks[64][65];   // K tile, pad-65 -> conflict-free
  __shared__ float Vs[64][65];
  __shared__ float Rst[80][65];  // staged r window
  __shared__ float pl[4][64];    // per-wave softmax probs

  int t0 = blockIdx.x * 16;
  int b = blockIdx.y >> 4;
  int h = blockIdx.y & 15;
  int tid = threadIdx.x;
  int lane = tid & 63;
  int wave = tid >> 6;

  float rwbv = rwb[h * 64 + lane];
  float rrbv = rrb[h * 64 + lane];
  for (int i = wave; i < 17; i += 4) {
    int t = t0 + i;
    float qv = (t < T_SEQ)
                   ? qkv[((long long)t * B_SZ + b) * E3 + h * 64 + lane]
                   : 0.f;
    if (i < 16) qw[i][lane] = qv + rwbv;
    qr[i][lane] = qv + rrbv;
  }

  float m_r[4], l_r[4], acc_r[4];
#pragma unroll
  for (int r2 = 0; r2 < 4; ++r2) {
    m_r[r2] = -1e30f; l_r[r2] = 0.f; acc_r[r2] = 0.f;
  }

  __syncthreads();

  for (int s0 = 0; s0 < T_SEQ; s0 += 64) {
    // stage K/V tile (coalesced 256B rows)
    for (int i = wave; i < 64; i += 4) {
      long long base = ((long long)(s0 + i) * B_SZ + b) * E3 + h * 64 + lane;
      Ks[i][lane] = qkv[base + E_DIM];
      Vs[i][lane] = qkv[base + 2 * E_DIM];
    }
    // stage R window: row ib holds r[g] if g<=1023 else r[g-1025]; the two
    // uses are disjoint by construction (g==1024 is the zeroed mid case).
    int cm0 = 1008 + s0 - t0;
    for (int i = wave; i < 79; i += 4) {
      int g = cm0 + i;
      int col = (g <= 1023) ? g : (g - 1025);
      if (col >= 0 && col <= 1023)
        Rst[i][lane] = rbuf[(long long)col * E_DIM + h * 64 + lane];
    }
    __syncthreads();

#pragma unroll
    for (int rr = 0; rr < 4; ++rr) {
      int tl = wave * 4 + rr;
      int t = t0 + tl;
      int s = s0 + lane;
      bool lower = (s <= t);
      bool mid = (s == t + 1);
      int rowq = lower ? tl : (tl + 1);
      int ib = 15 + lane - tl;   // 0..78
      float sAC = 0.f, sBD = 0.f;
#pragma unroll 8
      for (int d = 0; d < 64; ++d) {
        sAC = fmaf(qw[tl][d], Ks[lane][d], sAC);
        sBD = fmaf(qr[rowq][d], Rst[ib][d], sBD);
      }
      if (mid) sBD = 0.f;
      float sc = (sAC + sBD) * 0.125f;
      // wave-wide max
      float mt = sc;
#pragma unroll
      for (int off = 32; off >= 1; off >>= 1)
        mt = fmaxf(mt, __shfl_xor(mt, off));
      float mnew = fmaxf(m_r[rr], mt);
      float alpha = __expf(m_r[rr] - mnew);
      float p = __expf(sc - mnew);
      float ps = p;
#pragma unroll
      for (int off = 32; off >= 1; off >>= 1) ps += __shfl_xor(ps, off);
      m_r[rr] = mnew;
      l_r[rr] = l_r[rr] * alpha + ps;
      pl[wave][lane] = p;
      __asm__ volatile("s_waitcnt lgkmcnt(0)" ::: "memory");
      // PV: lane = d now
      float a2 = 0.f;
#pragma unroll 8
      for (int ss2 = 0; ss2 < 64; ++ss2)
        a2 = fmaf(pl[wave][ss2], Vs[ss2][lane], a2);
      acc_r[rr] = acc_r[rr] * alpha + a2;
    }
    __syncthreads();
  }

#pragma unroll
  for (int rr = 0; rr < 4; ++rr) {
    int t = t0 + wave * 4 + rr;
    outb[((long long)t * B_SZ + b) * E_DIM + h * 64 + lane] =
        acc_r[rr] / l_r[rr];
  }
}

// ---------------- launch ----------------
extern "C" void kernel_launch(void* const* d_in, const int* in_sizes, int n_in,
                              void* d_out, int out_size, void* d_ws,
                              size_t ws_size, hipStream_t stream) {
  const float* input = (const float*)d_in[0];   // [T,B,E]
  const float* pos   = (const float*)d_in[1];   // [T,1,E]
  const int*   idx   = (const int*)d_in[2];
  const float* in_w  = (const float*)d_in[3];   // [3E,E]
  const float* in_b  = (const float*)d_in[4];
  const float* out_w = (const float*)d_in[5];   // [E,E]
  const float* out_b = (const float*)d_in[6];
  const float* pos_w = (const float*)d_in[7];   // [E,E]
  const float* pos_b = (const float*)d_in[8];
  const float* r_i   = (const float*)d_in[9];
  const float* s_i   = (const float*)d_in[10];
  const float* r_p   = (const float*)d_in[11];
  const float* s_p   = (const float*)d_in[12];
  const float* r_o   = (const float*)d_in[13];
  const float* s_o   = (const float*)d_in[14];
  const float* rm_i  = (const float*)d_in[15];
  const float* sm_i  = (const float*)d_in[16];
  const float* rm_p  = (const float*)d_in[17];
  const float* sm_p  = (const float*)d_in[18];
  const float* rm_o  = (const float*)d_in[19];
  const float* sm_o  = (const float*)d_in[20];
  const float* rwb   = (const float*)d_in[21];  // [H,D]
  const float* rrb   = (const float*)d_in[22];  // [H,D]
  float* out = (float*)d_out;

  // workspace layout (floats)
  float* f0   = (float*)d_ws;
  float* Wi   = f0;                       // 3072*1024
  float* Wp   = Wi + (long long)E3 * E_DIM;       // 1024*1024
  float* Wo   = Wp + (long long)E_DIM * E_DIM;
  float* qkv  = Wo + (long long)E_DIM * E_DIM;    // 4096*3072
  float* rbuf = qkv + (long long)T_SEQ * B_SZ * E3;  // 1024*1024
  // attn_out aliases Wi+Wp (both dead by then); exactly 4096*1024 floats.
  float* attn_out = f0;

  // 1) factorized weights
  {
    long long n1 = (long long)E3 * E_DIM;
    factorize_kernel<<<(n1 + 255) / 256, 256, 0, stream>>>(
        in_w, rm_i, sm_i, r_i, s_i, idx, Wi, E3, E_DIM);
    long long n2 = (long long)E_DIM * E_DIM;
    factorize_kernel<<<(n2 + 255) / 256, 256, 0, stream>>>(
        pos_w, rm_p, sm_p, r_p, s_p, idx, Wp, E_DIM, E_DIM);
    factorize_kernel<<<(n2 + 255) / 256, 256, 0, stream>>>(
        out_w, rm_o, sm_o, r_o, s_o, idx, Wo, E_DIM, E_DIM);
  }
  // 2) qkv = input @ Wi^T + bias   [4096, 3072]
  gemm_abt_kernel<<<dim3(E3 / 64, (T_SEQ * B_SZ) / 64), 256, 0, stream>>>(
      input, Wi, in_b, qkv, T_SEQ * B_SZ, E3, E_DIM);
  // 3) rbuf = pos @ Wp^T + bias    [1024, 1024]
  gemm_abt_kernel<<<dim3(E_DIM / 64, T_SEQ / 64), 256, 0, stream>>>(
      pos, Wp, pos_b, rbuf, T_SEQ, E_DIM, E_DIM);
  // 4) fused attention -> attn_out [T*B, E]
  attn_kernel<<<dim3(T_SEQ / 16, B_SZ * H_DIM), 256, 0, stream>>>(
      qkv, rbuf, rwb, rrb, attn_out);
  // 5) out = attn_out @ Wo^T + bias
  gemm_abt_kernel<<<dim3(E_DIM / 64, (T_SEQ * B_SZ) / 64), 256, 0, stream>>>(
      attn_out, Wo, out_b, out, T_SEQ * B_SZ, E_DIM, E_DIM);
}

// Round 3
// 1190.302 us; speedup vs baseline: 2.0614x; 2.0614x over previous
//
#include <hip/hip_runtime.h>
#include <math.h>

#define E_DIM  1024
#define H_DIM  16
#define D_DIM  64
#define T_SEQ  1024
#define B_SZ   4
#define E3     3072
#define R_RANK 4

// ---------------- weight factorization ----------------
__global__ void factorize_kernel(const float* __restrict__ W,
                                 const float* __restrict__ rm,
                                 const float* __restrict__ sm,
                                 const float* __restrict__ r,
                                 const float* __restrict__ s,
                                 const int* __restrict__ idxp,
                                 float* __restrict__ out,
                                 int A, int Bc) {
  int idx = idxp[0];
  long long i = (long long)blockIdx.x * blockDim.x + threadIdx.x;
  long long total = (long long)A * Bc;
  if (i >= total) return;
  int a = (int)(i / Bc);
  int b = (int)(i % Bc);
  float acc = W[i] * rm[(long long)idx * A + a] * sm[(long long)idx * Bc + b];
#pragma unroll
  for (int k = 0; k < R_RANK; ++k) {
    acc += r[((long long)idx * R_RANK + k) * A + a] *
           s[((long long)idx * R_RANK + k) * Bc + b];
  }
  out[i] = acc;
}

// ---------------- GEMM: C[M,N] = A[M,K] * B[N,K]^T + bias[N] ----------------
__global__ __launch_bounds__(256) void gemm_abt_kernel(
    const float* __restrict__ A, const float* __restrict__ Bm,
    const float* __restrict__ bias, float* __restrict__ C,
    int M, int N, int K) {
  __shared__ float As[16][68];
  __shared__ float Bs[16][68];
  int tid = threadIdx.x;
  int tx = tid & 15, ty = tid >> 4;
  int m0 = blockIdx.y * 64, n0 = blockIdx.x * 64;
  int lrow = tid >> 2;
  int lk = (tid & 3) << 2;
  const float* Ag = A + (long long)(m0 + lrow) * K + lk;
  const float* Bg = Bm + (long long)(n0 + lrow) * K + lk;
  float acc[4][4] = {};
  for (int k0 = 0; k0 < K; k0 += 16) {
    float4 av = *(const float4*)(Ag + k0);
    float4 bv = *(const float4*)(Bg + k0);
    __syncthreads();
    As[lk + 0][lrow] = av.x; As[lk + 1][lrow] = av.y;
    As[lk + 2][lrow] = av.z; As[lk + 3][lrow] = av.w;
    Bs[lk + 0][lrow] = bv.x; Bs[lk + 1][lrow] = bv.y;
    Bs[lk + 2][lrow] = bv.z; Bs[lk + 3][lrow] = bv.w;
    __syncthreads();
#pragma unroll
    for (int kk = 0; kk < 16; ++kk) {
      float4 a4 = *(const float4*)&As[kk][ty << 2];
      float4 b4 = *(const float4*)&Bs[kk][tx << 2];
      float aa[4] = {a4.x, a4.y, a4.z, a4.w};
      float bb[4] = {b4.x, b4.y, b4.z, b4.w};
#pragma unroll
      for (int i2 = 0; i2 < 4; ++i2)
#pragma unroll
        for (int j2 = 0; j2 < 4; ++j2)
          acc[i2][j2] = fmaf(aa[i2], bb[j2], acc[i2][j2]);
    }
  }
#pragma unroll
  for (int i2 = 0; i2 < 4; ++i2) {
    int m = m0 + (ty << 2) + i2;
    int n = n0 + (tx << 2);
    float4 o;
    o.x = acc[i2][0] + bias[n + 0];
    o.y = acc[i2][1] + bias[n + 1];
    o.z = acc[i2][2] + bias[n + 2];
    o.w = acc[i2][3] + bias[n + 3];
    *(float4*)&C[(long long)m * N + n] = o;
  }
}

// ---------------- fused rel-shift attention, register-blocked ----------------
// Grid: (T/64, B*H), 256 threads. Per block: 64 query rows, iterate s-tiles of
// 64. Score tile 64x64 computed 4x4 per thread (tx = s-group, ty = t-group).
// rel_shift analytic: g = 1023+s-t; g<=1023 -> r[g]; g==1024 -> 0 (row zeroed
// in LDS); g>=1025 -> r[g-1025] with q-row t+1. Bias terms folded out:
// (q+rwb).k = q.k + ACb[s]; (q+rrb).r = q.r + BDb[w].
__global__ __launch_bounds__(256) void attn2_kernel(
    const float* __restrict__ qkv, const float* __restrict__ rbuf,
    const float* __restrict__ rwb, const float* __restrict__ rrb,
    float* __restrict__ outb) {
  __shared__ __align__(16) float qT[64][68];     // q^T, cols t0..t0+64
  __shared__ __align__(16) float region[8704];   // phased: {KTh,RTh} | {Pls,Vs}
  __shared__ __align__(16) float ACb[64];
  __shared__ __align__(16) float BDb[128];
  __shared__ float rwbs[64];
  __shared__ float rrbs[64];
  float (*KTh)[68]  = (float(*)[68])region;              // 32 x 68
  float (*RTh)[132] = (float(*)[132])(region + 32 * 68); // 32 x 132
  float (*Pls)[68]  = (float(*)[68])region;              // 64 x 68 (P^T: [s][t])
  float (*Vs)[68]   = (float(*)[68])(region + 64 * 68);  // 64 x 68 ([s][d])

  const int t0 = blockIdx.x * 64;
  const int b = blockIdx.y >> 4, h = blockIdx.y & 15;
  const int tid = threadIdx.x;
  const int tx = tid & 15, ty = tid >> 4;
  const int wv = tid >> 6, ln = tid & 63;
  const int wb = 60 + 4 * (tx - ty);   // R-window base for this thread, 0..120

  if (tid < 64) rwbs[tid] = rwb[h * 64 + tid];
  else if (tid < 128) rrbs[tid - 64] = rrb[h * 64 + tid - 64];

  // stage qT (transposed), cols 0..64
  {
    int d0 = (tid & 15) * 4, tl = tid >> 4;
#pragma unroll
    for (int p = 0; p < 5; ++p) {
      int tc = tl + p * 16;
      if (tc <= 64) {
        int t = t0 + tc;
        float4 v = make_float4(0.f, 0.f, 0.f, 0.f);
        if (t < T_SEQ)
          v = *(const float4*)&qkv[((long long)t * B_SZ + b) * E3 + h * 64 + d0];
        qT[d0 + 0][tc] = v.x; qT[d0 + 1][tc] = v.y;
        qT[d0 + 2][tc] = v.z; qT[d0 + 3][tc] = v.w;
      }
    }
  }

  float m_r[4], l_r[4], acc[4][4];
#pragma unroll
  for (int i2 = 0; i2 < 4; ++i2) {
    m_r[i2] = -1e30f; l_r[i2] = 0.f;
#pragma unroll
    for (int j2 = 0; j2 < 4; ++j2) acc[i2][j2] = 0.f;
  }

  for (int s0 = 0; s0 < T_SEQ; s0 += 64) {
    float accS[4][4];
#pragma unroll
    for (int i2 = 0; i2 < 4; ++i2)
#pragma unroll
      for (int j2 = 0; j2 < 4; ++j2) accS[i2][j2] = 0.f;
    float acb = 0.f, bdb = 0.f;
    const int cm0 = 960 + s0 - t0;
    const int crit = t0 - s0 + 4 * (ty - tx);  // lower iff j2-i2 <= crit

    for (int dh = 0; dh < 2; ++dh) {
      __syncthreads();  // region free of prior-phase readers
      // stage K^T half
      {
        int d0 = (tid & 7) * 4, sl = tid >> 3;
#pragma unroll
        for (int p = 0; p < 2; ++p) {
          int s = sl + p * 32;
          float4 v = *(const float4*)&qkv[((long long)(s0 + s) * B_SZ + b) * E3 +
                                          E_DIM + h * 64 + dh * 32 + d0];
          KTh[d0 + 0][s] = v.x; KTh[d0 + 1][s] = v.y;
          KTh[d0 + 2][s] = v.z; KTh[d0 + 3][s] = v.w;
        }
      }
      // stage R^T half (window rows 0..127; invalid g -> 0)
      {
        int d0 = (tid & 7) * 4, wl = tid >> 3;
#pragma unroll
        for (int p = 0; p < 4; ++p) {
          int w = wl + p * 32;
          int g = cm0 + w;
          int col = (g <= 1023) ? g : (g - 1025);
          float4 v = make_float4(0.f, 0.f, 0.f, 0.f);
          if (col >= 0 && col < 1024)
            v = *(const float4*)&rbuf[(long long)col * E_DIM + h * 64 + dh * 32 + d0];
          RTh[d0 + 0][w] = v.x; RTh[d0 + 1][w] = v.y;
          RTh[d0 + 2][w] = v.z; RTh[d0 + 3][w] = v.w;
        }
      }
      __syncthreads();
      // score GEMM over this d-half
      for (int dl = 0; dl < 32; ++dl) {
        int dg = dh * 32 + dl;
        float4 a4 = *(const float4*)&qT[dg][ty * 4];
        float a5v = qT[dg][ty * 4 + 4];
        float4 k4 = *(const float4*)&KTh[dl][tx * 4];
        float4 r0 = *(const float4*)&RTh[dl][wb];
        float4 r1 = *(const float4*)&RTh[dl][wb + 4];
        float a[5] = {a4.x, a4.y, a4.z, a4.w, a5v};
        float kk[4] = {k4.x, k4.y, k4.z, k4.w};
        float rr[8] = {r0.x, r0.y, r0.z, r0.w, r1.x, r1.y, r1.z, r1.w};
#pragma unroll
        for (int i2 = 0; i2 < 4; ++i2) {
#pragma unroll
          for (int j2 = 0; j2 < 4; ++j2) {
            accS[i2][j2] = fmaf(a[i2], kk[j2], accS[i2][j2]);
            float qv = (j2 - i2 <= crit) ? a[i2] : a[i2 + 1];
            accS[i2][j2] = fmaf(qv, rr[3 + j2 - i2], accS[i2][j2]);
          }
        }
      }
      // bias side-jobs (waves 0-2)
      if (wv == 0) {
        for (int dl = 0; dl < 32; ++dl)
          acb = fmaf(rwbs[dh * 32 + dl], KTh[dl][ln], acb);
      } else if (wv == 1) {
        for (int dl = 0; dl < 32; ++dl)
          bdb = fmaf(rrbs[dh * 32 + dl], RTh[dl][ln], bdb);
      } else if (wv == 2) {
        for (int dl = 0; dl < 32; ++dl)
          bdb = fmaf(rrbs[dh * 32 + dl], RTh[dl][64 + ln], bdb);
      }
    }
    if (wv == 0) ACb[ln] = acb;
    else if (wv == 1) BDb[ln] = bdb;
    else if (wv == 2) BDb[64 + ln] = bdb;
    __syncthreads();

    // assemble scores + online softmax
    float4 ab4 = *(const float4*)&ACb[tx * 4];
    float4 bd0 = *(const float4*)&BDb[wb];
    float4 bd1 = *(const float4*)&BDb[wb + 4];
    float abA[4] = {ab4.x, ab4.y, ab4.z, ab4.w};
    float bdA[8] = {bd0.x, bd0.y, bd0.z, bd0.w, bd1.x, bd1.y, bd1.z, bd1.w};
    float p[4][4];
#pragma unroll
    for (int i2 = 0; i2 < 4; ++i2) {
      float sc[4];
#pragma unroll
      for (int j2 = 0; j2 < 4; ++j2)
        sc[j2] = (accS[i2][j2] + abA[j2] + bdA[3 + j2 - i2]) * 0.125f;
      float mt = fmaxf(fmaxf(sc[0], sc[1]), fmaxf(sc[2], sc[3]));
#pragma unroll
      for (int off = 8; off >= 1; off >>= 1)
        mt = fmaxf(mt, __shfl_xor(mt, off));
      float mnew = fmaxf(m_r[i2], mt);
      float alpha = __expf(m_r[i2] - mnew);
      m_r[i2] = mnew;
      float ps = 0.f;
#pragma unroll
      for (int j2 = 0; j2 < 4; ++j2) {
        p[i2][j2] = __expf(sc[j2] - mnew);
        ps += p[i2][j2];
      }
#pragma unroll
      for (int off = 8; off >= 1; off >>= 1) ps += __shfl_xor(ps, off);
      l_r[i2] = l_r[i2] * alpha + ps;
#pragma unroll
      for (int j2 = 0; j2 < 4; ++j2) acc[i2][j2] *= alpha;
    }
    // write P^T and stage V (region re-used; all GEMM reads done at last bar)
#pragma unroll
    for (int i2 = 0; i2 < 4; ++i2)
#pragma unroll
      for (int j2 = 0; j2 < 4; ++j2)
        Pls[tx * 4 + j2][ty * 4 + i2] = p[i2][j2];
    {
      int d0 = (tid & 15) * 4, sl = tid >> 4;
#pragma unroll
      for (int pp = 0; pp < 4; ++pp) {
        int s = sl + pp * 16;
        float4 v = *(const float4*)&qkv[((long long)(s0 + s) * B_SZ + b) * E3 +
                                        2 * E_DIM + h * 64 + d0];
        *(float4*)&Vs[s][d0] = v;
      }
    }
    __syncthreads();
    // PV GEMM: acc[t][d] += sum_s P^T[s][t] * V[s][d]
    for (int s = 0; s < 64; ++s) {
      float4 p4 = *(const float4*)&Pls[s][ty * 4];
      float4 v4 = *(const float4*)&Vs[s][tx * 4];
      float pa[4] = {p4.x, p4.y, p4.z, p4.w};
      float va[4] = {v4.x, v4.y, v4.z, v4.w};
#pragma unroll
      for (int i2 = 0; i2 < 4; ++i2)
#pragma unroll
        for (int j2 = 0; j2 < 4; ++j2)
          acc[i2][j2] = fmaf(pa[i2], va[j2], acc[i2][j2]);
    }
  }

#pragma unroll
  for (int i2 = 0; i2 < 4; ++i2) {
    float inv = 1.f / l_r[i2];
    int t = t0 + ty * 4 + i2;
    float4 o;
    o.x = acc[i2][0] * inv; o.y = acc[i2][1] * inv;
    o.z = acc[i2][2] * inv; o.w = acc[i2][3] * inv;
    *(float4*)&outb[((long long)t * B_SZ + b) * E_DIM + h * 64 + tx * 4] = o;
  }
}

// ---------------- launch ----------------
extern "C" void kernel_launch(void* const* d_in, const int* in_sizes, int n_in,
                              void* d_out, int out_size, void* d_ws,
                              size_t ws_size, hipStream_t stream) {
  const float* input = (const float*)d_in[0];
  const float* pos   = (const float*)d_in[1];
  const int*   idx   = (const int*)d_in[2];
  const float* in_w  = (const float*)d_in[3];
  const float* in_b  = (const float*)d_in[4];
  const float* out_w = (const float*)d_in[5];
  const float* out_b = (const float*)d_in[6];
  const float* pos_w = (const float*)d_in[7];
  const float* pos_b = (const float*)d_in[8];
  const float* r_i   = (const float*)d_in[9];
  const float* s_i   = (const float*)d_in[10];
  const float* r_p   = (const float*)d_in[11];
  const float* s_p   = (const float*)d_in[12];
  const float* r_o   = (const float*)d_in[13];
  const float* s_o   = (const float*)d_in[14];
  const float* rm_i  = (const float*)d_in[15];
  const float* sm_i  = (const float*)d_in[16];
  const float* rm_p  = (const float*)d_in[17];
  const float* sm_p  = (const float*)d_in[18];
  const float* rm_o  = (const float*)d_in[19];
  const float* sm_o  = (const float*)d_in[20];
  const float* rwb   = (const float*)d_in[21];
  const float* rrb   = (const float*)d_in[22];
  float* out = (float*)d_out;

  float* f0   = (float*)d_ws;
  float* Wi   = f0;
  float* Wp   = Wi + (long long)E3 * E_DIM;
  float* Wo   = Wp + (long long)E_DIM * E_DIM;
  float* qkv  = Wo + (long long)E_DIM * E_DIM;
  float* rbuf = qkv + (long long)T_SEQ * B_SZ * E3;
  float* attn_out = f0;  // aliases Wi+Wp (dead by then)

  {
    long long n1 = (long long)E3 * E_DIM;
    factorize_kernel<<<(n1 + 255) / 256, 256, 0, stream>>>(
        in_w, rm_i, sm_i, r_i, s_i, idx, Wi, E3, E_DIM);
    long long n2 = (long long)E_DIM * E_DIM;
    factorize_kernel<<<(n2 + 255) / 256, 256, 0, stream>>>(
        pos_w, rm_p, sm_p, r_p, s_p, idx, Wp, E_DIM, E_DIM);
    factorize_kernel<<<(n2 + 255) / 256, 256, 0, stream>>>(
        out_w, rm_o, sm_o, r_o, s_o, idx, Wo, E_DIM, E_DIM);
  }
  gemm_abt_kernel<<<dim3(E3 / 64, (T_SEQ * B_SZ) / 64), 256, 0, stream>>>(
      input, Wi, in_b, qkv, T_SEQ * B_SZ, E3, E_DIM);
  gemm_abt_kernel<<<dim3(E_DIM / 64, T_SEQ / 64), 256, 0, stream>>>(
      pos, Wp, pos_b, rbuf, T_SEQ, E_DIM, E_DIM);
  attn2_kernel<<<dim3(T_SEQ / 64, B_SZ * H_DIM), 256, 0, stream>>>(
      qkv, rbuf, rwb, rrb, attn_out);
  gemm_abt_kernel<<<dim3(E_DIM / 64, (T_SEQ * B_SZ) / 64), 256, 0, stream>>>(
      attn_out, Wo, out_b, out, T_SEQ * B_SZ, E_DIM, E_DIM);
}

// Round 4
// 781.962 us; speedup vs baseline: 3.1378x; 1.5222x over previous
//
#include <hip/hip_runtime.h>
#include <hip/hip_bf16.h>
#include <math.h>

#define E_DIM  1024
#define H_DIM  16
#define D_DIM  64
#define T_SEQ  1024
#define B_SZ   4
#define E3     3072
#define R_RANK 4

typedef __attribute__((ext_vector_type(8))) short bf16x8;
typedef __attribute__((ext_vector_type(4))) float f32x4;

static __device__ __forceinline__ ushort f2bf(float x) {
  __hip_bfloat16 h = __float2bfloat16(x);
  return *(ushort*)&h;
}

// ---------------- cast f32 -> bf16 (vectorized) ----------------
__global__ void cast_bf16_kernel(const float* __restrict__ in,
                                 ushort* __restrict__ out, long long n4) {
  long long i = (long long)blockIdx.x * blockDim.x + threadIdx.x;
  if (i >= n4) return;
  float4 v = *(const float4*)(in + i * 4);
  ushort4 o;
  o.x = f2bf(v.x); o.y = f2bf(v.y); o.z = f2bf(v.z); o.w = f2bf(v.w);
  *(ushort4*)(out + i * 4) = o;
}

// ---------------- weight factorization (emits bf16) ----------------
__global__ void factorize_kernel(const float* __restrict__ W,
                                 const float* __restrict__ rm,
                                 const float* __restrict__ sm,
                                 const float* __restrict__ r,
                                 const float* __restrict__ s,
                                 const int* __restrict__ idxp,
                                 ushort* __restrict__ out,
                                 int A, int Bc) {
  int idx = idxp[0];
  long long i = (long long)blockIdx.x * blockDim.x + threadIdx.x;
  long long total = (long long)A * Bc;
  if (i >= total) return;
  int a = (int)(i / Bc);
  int b = (int)(i % Bc);
  float acc = W[i] * rm[(long long)idx * A + a] * sm[(long long)idx * Bc + b];
#pragma unroll
  for (int k = 0; k < R_RANK; ++k) {
    acc += r[((long long)idx * R_RANK + k) * A + a] *
           s[((long long)idx * R_RANK + k) * Bc + b];
  }
  out[i] = f2bf(acc);
}

// ---------------- bf16 MFMA GEMM: C[M,N] = A[M,K] * B[N,K]^T + bias ----------
// 128x128 tile, BK=32, 256 threads (4 waves, 2x2 of 64x64), 16x16x32 MFMA.
// LDS row stride 40 ushorts (80B): b128 reads/writes land on the uniform
// bank floor (gcd(20,32)=4 spreads 4-dword groups evenly).
__global__ __launch_bounds__(256) void gemm_mfma_kernel(
    const ushort* __restrict__ A, const ushort* __restrict__ B,
    const float* __restrict__ bias, float* __restrict__ C,
    int M, int N, int K) {
  __shared__ __align__(16) ushort As[128 * 40];
  __shared__ __align__(16) ushort Bs[128 * 40];
  const int tid = threadIdx.x;
  const int l = tid & 63, w = tid >> 6;
  const int m0 = blockIdx.y * 128, n0 = blockIdx.x * 128;
  const int mw = (w >> 1) * 64, nw = (w & 1) * 64;
  const int fr = l & 15, fq = l >> 4;

  f32x4 acc[4][4];
#pragma unroll
  for (int i = 0; i < 4; ++i)
#pragma unroll
    for (int j = 0; j < 4; ++j)
#pragma unroll
      for (int q = 0; q < 4; ++q) acc[i][j][q] = 0.f;

  for (int k0 = 0; k0 < K; k0 += 32) {
    __syncthreads();
#pragma unroll
    for (int p = 0; p < 2; ++p) {
      int ci = p * 256 + tid;
      int row = ci >> 2, c = ci & 3;
      float4 av = *(const float4*)(A + (long long)(m0 + row) * K + k0 + c * 8);
      *(float4*)(As + row * 40 + c * 8) = av;
      float4 bv = *(const float4*)(B + (long long)(n0 + row) * K + k0 + c * 8);
      *(float4*)(Bs + row * 40 + c * 8) = bv;
    }
    __syncthreads();
    bf16x8 af[4], bfr[4];
#pragma unroll
    for (int i = 0; i < 4; ++i) {
      af[i]  = *(const bf16x8*)(As + (mw + i * 16 + fr) * 40 + fq * 8);
      bfr[i] = *(const bf16x8*)(Bs + (nw + i * 16 + fr) * 40 + fq * 8);
    }
#pragma unroll
    for (int i = 0; i < 4; ++i)
#pragma unroll
      for (int j = 0; j < 4; ++j)
        acc[i][j] = __builtin_amdgcn_mfma_f32_16x16x32_bf16(
            af[i], bfr[j], acc[i][j], 0, 0, 0);
  }
  // C/D layout: col = n-index = lane&15, row = m-index = (lane>>4)*4 + reg
#pragma unroll
  for (int i = 0; i < 4; ++i) {
#pragma unroll
    for (int j = 0; j < 4; ++j) {
      int n = n0 + nw + j * 16 + fr;
      float bv = bias[n];
#pragma unroll
      for (int q = 0; q < 4; ++q) {
        int m = m0 + mw + i * 16 + fq * 4 + q;
        C[(long long)m * N + n] = acc[i][j][q] + bv;
      }
    }
  }
}

// ---------------- fused rel-shift attention, register-blocked f32 ------------
// (unchanged from round 3 except: output emitted as bf16 for the out-proj GEMM)
__global__ __launch_bounds__(256) void attn2_kernel(
    const float* __restrict__ qkv, const float* __restrict__ rbuf,
    const float* __restrict__ rwb, const float* __restrict__ rrb,
    ushort* __restrict__ outb) {
  __shared__ __align__(16) float qT[64][68];
  __shared__ __align__(16) float region[8704];
  __shared__ __align__(16) float ACb[64];
  __shared__ __align__(16) float BDb[128];
  __shared__ float rwbs[64];
  __shared__ float rrbs[64];
  float (*KTh)[68]  = (float(*)[68])region;
  float (*RTh)[132] = (float(*)[132])(region + 32 * 68);
  float (*Pls)[68]  = (float(*)[68])region;
  float (*Vs)[68]   = (float(*)[68])(region + 64 * 68);

  const int t0 = blockIdx.x * 64;
  const int b = blockIdx.y >> 4, h = blockIdx.y & 15;
  const int tid = threadIdx.x;
  const int tx = tid & 15, ty = tid >> 4;
  const int wv = tid >> 6, ln = tid & 63;
  const int wb = 60 + 4 * (tx - ty);

  if (tid < 64) rwbs[tid] = rwb[h * 64 + tid];
  else if (tid < 128) rrbs[tid - 64] = rrb[h * 64 + tid - 64];

  {
    int d0 = (tid & 15) * 4, tl = tid >> 4;
#pragma unroll
    for (int p = 0; p < 5; ++p) {
      int tc = tl + p * 16;
      if (tc <= 64) {
        int t = t0 + tc;
        float4 v = make_float4(0.f, 0.f, 0.f, 0.f);
        if (t < T_SEQ)
          v = *(const float4*)&qkv[((long long)t * B_SZ + b) * E3 + h * 64 + d0];
        qT[d0 + 0][tc] = v.x; qT[d0 + 1][tc] = v.y;
        qT[d0 + 2][tc] = v.z; qT[d0 + 3][tc] = v.w;
      }
    }
  }

  float m_r[4], l_r[4], acc[4][4];
#pragma unroll
  for (int i2 = 0; i2 < 4; ++i2) {
    m_r[i2] = -1e30f; l_r[i2] = 0.f;
#pragma unroll
    for (int j2 = 0; j2 < 4; ++j2) acc[i2][j2] = 0.f;
  }

  for (int s0 = 0; s0 < T_SEQ; s0 += 64) {
    float accS[4][4];
#pragma unroll
    for (int i2 = 0; i2 < 4; ++i2)
#pragma unroll
      for (int j2 = 0; j2 < 4; ++j2) accS[i2][j2] = 0.f;
    float acb = 0.f, bdb = 0.f;
    const int cm0 = 960 + s0 - t0;
    const int crit = t0 - s0 + 4 * (ty - tx);

    for (int dh = 0; dh < 2; ++dh) {
      __syncthreads();
      {
        int d0 = (tid & 7) * 4, sl = tid >> 3;
#pragma unroll
        for (int p = 0; p < 2; ++p) {
          int s = sl + p * 32;
          float4 v = *(const float4*)&qkv[((long long)(s0 + s) * B_SZ + b) * E3 +
                                          E_DIM + h * 64 + dh * 32 + d0];
          KTh[d0 + 0][s] = v.x; KTh[d0 + 1][s] = v.y;
          KTh[d0 + 2][s] = v.z; KTh[d0 + 3][s] = v.w;
        }
      }
      {
        int d0 = (tid & 7) * 4, wl = tid >> 3;
#pragma unroll
        for (int p = 0; p < 4; ++p) {
          int w = wl + p * 32;
          int g = cm0 + w;
          int col = (g <= 1023) ? g : (g - 1025);
          float4 v = make_float4(0.f, 0.f, 0.f, 0.f);
          if (col >= 0 && col < 1024)
            v = *(const float4*)&rbuf[(long long)col * E_DIM + h * 64 + dh * 32 + d0];
          RTh[d0 + 0][w] = v.x; RTh[d0 + 1][w] = v.y;
          RTh[d0 + 2][w] = v.z; RTh[d0 + 3][w] = v.w;
        }
      }
      __syncthreads();
      for (int dl = 0; dl < 32; ++dl) {
        int dg = dh * 32 + dl;
        float4 a4 = *(const float4*)&qT[dg][ty * 4];
        float a5v = qT[dg][ty * 4 + 4];
        float4 k4 = *(const float4*)&KTh[dl][tx * 4];
        float4 r0 = *(const float4*)&RTh[dl][wb];
        float4 r1 = *(const float4*)&RTh[dl][wb + 4];
        float a[5] = {a4.x, a4.y, a4.z, a4.w, a5v};
        float kk[4] = {k4.x, k4.y, k4.z, k4.w};
        float rr[8] = {r0.x, r0.y, r0.z, r0.w, r1.x, r1.y, r1.z, r1.w};
#pragma unroll
        for (int i2 = 0; i2 < 4; ++i2) {
#pragma unroll
          for (int j2 = 0; j2 < 4; ++j2) {
            accS[i2][j2] = fmaf(a[i2], kk[j2], accS[i2][j2]);
            float qv = (j2 - i2 <= crit) ? a[i2] : a[i2 + 1];
            accS[i2][j2] = fmaf(qv, rr[3 + j2 - i2], accS[i2][j2]);
          }
        }
      }
      if (wv == 0) {
        for (int dl = 0; dl < 32; ++dl)
          acb = fmaf(rwbs[dh * 32 + dl], KTh[dl][ln], acb);
      } else if (wv == 1) {
        for (int dl = 0; dl < 32; ++dl)
          bdb = fmaf(rrbs[dh * 32 + dl], RTh[dl][ln], bdb);
      } else if (wv == 2) {
        for (int dl = 0; dl < 32; ++dl)
          bdb = fmaf(rrbs[dh * 32 + dl], RTh[dl][64 + ln], bdb);
      }
    }
    if (wv == 0) ACb[ln] = acb;
    else if (wv == 1) BDb[ln] = bdb;
    else if (wv == 2) BDb[64 + ln] = bdb;
    __syncthreads();

    float4 ab4 = *(const float4*)&ACb[tx * 4];
    float4 bd0 = *(const float4*)&BDb[wb];
    float4 bd1 = *(const float4*)&BDb[wb + 4];
    float abA[4] = {ab4.x, ab4.y, ab4.z, ab4.w};
    float bdA[8] = {bd0.x, bd0.y, bd0.z, bd0.w, bd1.x, bd1.y, bd1.z, bd1.w};
    float p[4][4];
#pragma unroll
    for (int i2 = 0; i2 < 4; ++i2) {
      float sc[4];
#pragma unroll
      for (int j2 = 0; j2 < 4; ++j2)
        sc[j2] = (accS[i2][j2] + abA[j2] + bdA[3 + j2 - i2]) * 0.125f;
      float mt = fmaxf(fmaxf(sc[0], sc[1]), fmaxf(sc[2], sc[3]));
#pragma unroll
      for (int off = 8; off >= 1; off >>= 1)
        mt = fmaxf(mt, __shfl_xor(mt, off));
      float mnew = fmaxf(m_r[i2], mt);
      float alpha = __expf(m_r[i2] - mnew);
      m_r[i2] = mnew;
      float ps = 0.f;
#pragma unroll
      for (int j2 = 0; j2 < 4; ++j2) {
        p[i2][j2] = __expf(sc[j2] - mnew);
        ps += p[i2][j2];
      }
#pragma unroll
      for (int off = 8; off >= 1; off >>= 1) ps += __shfl_xor(ps, off);
      l_r[i2] = l_r[i2] * alpha + ps;
#pragma unroll
      for (int j2 = 0; j2 < 4; ++j2) acc[i2][j2] *= alpha;
    }
#pragma unroll
    for (int i2 = 0; i2 < 4; ++i2)
#pragma unroll
      for (int j2 = 0; j2 < 4; ++j2)
        Pls[tx * 4 + j2][ty * 4 + i2] = p[i2][j2];
    {
      int d0 = (tid & 15) * 4, sl = tid >> 4;
#pragma unroll
      for (int pp = 0; pp < 4; ++pp) {
        int s = sl + pp * 16;
        float4 v = *(const float4*)&qkv[((long long)(s0 + s) * B_SZ + b) * E3 +
                                        2 * E_DIM + h * 64 + d0];
        *(float4*)&Vs[s][d0] = v;
      }
    }
    __syncthreads();
    for (int s = 0; s < 64; ++s) {
      float4 p4 = *(const float4*)&Pls[s][ty * 4];
      float4 v4 = *(const float4*)&Vs[s][tx * 4];
      float pa[4] = {p4.x, p4.y, p4.z, p4.w};
      float va[4] = {v4.x, v4.y, v4.z, v4.w};
#pragma unroll
      for (int i2 = 0; i2 < 4; ++i2)
#pragma unroll
        for (int j2 = 0; j2 < 4; ++j2)
          acc[i2][j2] = fmaf(pa[i2], va[j2], acc[i2][j2]);
    }
  }

#pragma unroll
  for (int i2 = 0; i2 < 4; ++i2) {
    float inv = 1.f / l_r[i2];
    int t = t0 + ty * 4 + i2;
    ushort4 o;
    o.x = f2bf(acc[i2][0] * inv); o.y = f2bf(acc[i2][1] * inv);
    o.z = f2bf(acc[i2][2] * inv); o.w = f2bf(acc[i2][3] * inv);
    *(ushort4*)&outb[((long long)t * B_SZ + b) * E_DIM + h * 64 + tx * 4] = o;
  }
}

// ---------------- launch ----------------
extern "C" void kernel_launch(void* const* d_in, const int* in_sizes, int n_in,
                              void* d_out, int out_size, void* d_ws,
                              size_t ws_size, hipStream_t stream) {
  const float* input = (const float*)d_in[0];
  const float* pos   = (const float*)d_in[1];
  const int*   idx   = (const int*)d_in[2];
  const float* in_w  = (const float*)d_in[3];
  const float* in_b  = (const float*)d_in[4];
  const float* out_w = (const float*)d_in[5];
  const float* out_b = (const float*)d_in[6];
  const float* pos_w = (const float*)d_in[7];
  const float* pos_b = (const float*)d_in[8];
  const float* r_i   = (const float*)d_in[9];
  const float* s_i   = (const float*)d_in[10];
  const float* r_p   = (const float*)d_in[11];
  const float* s_p   = (const float*)d_in[12];
  const float* r_o   = (const float*)d_in[13];
  const float* s_o   = (const float*)d_in[14];
  const float* rm_i  = (const float*)d_in[15];
  const float* sm_i  = (const float*)d_in[16];
  const float* rm_p  = (const float*)d_in[17];
  const float* sm_p  = (const float*)d_in[18];
  const float* rm_o  = (const float*)d_in[19];
  const float* sm_o  = (const float*)d_in[20];
  const float* rwb   = (const float*)d_in[21];
  const float* rrb   = (const float*)d_in[22];
  float* out = (float*)d_out;

  // workspace layout (bytes): total 72 MB
  char* base = (char*)d_ws;
  float*  qkv  = (float*)(base + 0);                    // 48 MB f32 [4096][3072]
  float*  rbuf = (float*)(base + 48ll * 1024 * 1024);   //  4 MB f32 [1024][1024]
  ushort* Wi   = (ushort*)(base + 52ll * 1024 * 1024);  //  6 MB bf16 [3072][1024]
  ushort* Wp   = (ushort*)(base + 58ll * 1024 * 1024);  //  2 MB bf16 [1024][1024]
  ushort* Wo   = (ushort*)(base + 60ll * 1024 * 1024);  //  2 MB bf16 [1024][1024]
  ushort* ibf  = (ushort*)(base + 62ll * 1024 * 1024);  //  8 MB bf16 [4096][1024]
  ushort* pbf  = (ushort*)(base + 70ll * 1024 * 1024);  //  2 MB bf16 [1024][1024]
  ushort* abf  = ibf;  // attn_out bf16 aliases ibf (dead after qkv GEMM)

  // casts
  cast_bf16_kernel<<<(T_SEQ * B_SZ * E_DIM / 4 + 255) / 256, 256, 0, stream>>>(
      input, ibf, (long long)T_SEQ * B_SZ * E_DIM / 4);
  cast_bf16_kernel<<<(T_SEQ * E_DIM / 4 + 255) / 256, 256, 0, stream>>>(
      pos, pbf, (long long)T_SEQ * E_DIM / 4);
  // factorized weights (bf16)
  {
    long long n1 = (long long)E3 * E_DIM;
    factorize_kernel<<<(n1 + 255) / 256, 256, 0, stream>>>(
        in_w, rm_i, sm_i, r_i, s_i, idx, Wi, E3, E_DIM);
    long long n2 = (long long)E_DIM * E_DIM;
    factorize_kernel<<<(n2 + 255) / 256, 256, 0, stream>>>(
        pos_w, rm_p, sm_p, r_p, s_p, idx, Wp, E_DIM, E_DIM);
    factorize_kernel<<<(n2 + 255) / 256, 256, 0, stream>>>(
        out_w, rm_o, sm_o, r_o, s_o, idx, Wo, E_DIM, E_DIM);
  }
  // qkv = input @ Wi^T + bias   [4096, 3072] f32
  gemm_mfma_kernel<<<dim3(E3 / 128, (T_SEQ * B_SZ) / 128), 256, 0, stream>>>(
      ibf, Wi, in_b, qkv, T_SEQ * B_SZ, E3, E_DIM);
  // rbuf = pos @ Wp^T + bias    [1024, 1024] f32
  gemm_mfma_kernel<<<dim3(E_DIM / 128, T_SEQ / 128), 256, 0, stream>>>(
      pbf, Wp, pos_b, rbuf, T_SEQ, E_DIM, E_DIM);
  // fused attention -> abf (bf16)
  attn2_kernel<<<dim3(T_SEQ / 64, B_SZ * H_DIM), 256, 0, stream>>>(
      qkv, rbuf, rwb, rrb, abf);
  // out = attn_out @ Wo^T + bias
  gemm_mfma_kernel<<<dim3(E_DIM / 128, (T_SEQ * B_SZ) / 128), 256, 0, stream>>>(
      abf, Wo, out_b, out, T_SEQ * B_SZ, E_DIM, E_DIM);
}

// Round 6
// 278.632 us; speedup vs baseline: 8.8061x; 2.8064x over previous
//
#include <hip/hip_runtime.h>
#include <hip/hip_bf16.h>
#include <math.h>

#define E_DIM  1024
#define H_DIM  16
#define D_DIM  64
#define T_SEQ  1024
#define B_SZ   4
#define E3     3072
#define R_RANK 4

typedef __attribute__((ext_vector_type(8))) short bf16x8;
typedef __attribute__((ext_vector_type(8))) unsigned short u16x8;
typedef __attribute__((ext_vector_type(4))) float f32x4;

static __device__ __forceinline__ ushort f2bf(float x) {
  __hip_bfloat16 h = __float2bfloat16(x);
  return *(ushort*)&h;
}
static __device__ __forceinline__ float bf2f(ushort u) {
  unsigned int v = ((unsigned int)u) << 16;
  float f;
  __builtin_memcpy(&f, &v, 4);
  return f;
}

// ---------------- cast f32 -> bf16 ----------------
__global__ void cast_bf16_kernel(const float* __restrict__ in,
                                 ushort* __restrict__ out, long long n4) {
  long long i = (long long)blockIdx.x * blockDim.x + threadIdx.x;
  if (i >= n4) return;
  float4 v = *(const float4*)(in + i * 4);
  ushort4 o;
  o.x = f2bf(v.x); o.y = f2bf(v.y); o.z = f2bf(v.z); o.w = f2bf(v.w);
  *(ushort4*)(out + i * 4) = o;
}

// ---------------- weight factorization (emits bf16) ----------------
__global__ void factorize_kernel(const float* __restrict__ W,
                                 const float* __restrict__ rm,
                                 const float* __restrict__ sm,
                                 const float* __restrict__ r,
                                 const float* __restrict__ s,
                                 const int* __restrict__ idxp,
                                 ushort* __restrict__ out,
                                 int A, int Bc) {
  int idx = idxp[0];
  long long i = (long long)blockIdx.x * blockDim.x + threadIdx.x;
  long long total = (long long)A * Bc;
  if (i >= total) return;
  int a = (int)(i / Bc);
  int b = (int)(i % Bc);
  float acc = W[i] * rm[(long long)idx * A + a] * sm[(long long)idx * Bc + b];
#pragma unroll
  for (int k = 0; k < R_RANK; ++k) {
    acc += r[((long long)idx * R_RANK + k) * A + a] *
           s[((long long)idx * R_RANK + k) * Bc + b];
  }
  out[i] = f2bf(acc);
}

// ---------------- bf16 MFMA GEMM: C[M,N] = A[M,K] * B[N,K]^T + bias ----------
template <bool BF16OUT>
__global__ __launch_bounds__(256) void gemm_mfma_kernel(
    const ushort* __restrict__ A, const ushort* __restrict__ B,
    const float* __restrict__ bias, void* __restrict__ Cv,
    int M, int N, int K) {
  __shared__ __align__(16) ushort As[128 * 40];
  __shared__ __align__(16) ushort Bs[128 * 40];
  const int tid = threadIdx.x;
  const int l = tid & 63, w = tid >> 6;
  const int m0 = blockIdx.y * 128, n0 = blockIdx.x * 128;
  const int mw = (w >> 1) * 64, nw = (w & 1) * 64;
  const int fr = l & 15, fq = l >> 4;

  f32x4 acc[4][4];
#pragma unroll
  for (int i = 0; i < 4; ++i)
#pragma unroll
    for (int j = 0; j < 4; ++j)
#pragma unroll
      for (int q = 0; q < 4; ++q) acc[i][j][q] = 0.f;

  for (int k0 = 0; k0 < K; k0 += 32) {
    __syncthreads();
#pragma unroll
    for (int p = 0; p < 2; ++p) {
      int ci = p * 256 + tid;
      int row = ci >> 2, c = ci & 3;
      float4 av = *(const float4*)(A + (long long)(m0 + row) * K + k0 + c * 8);
      *(float4*)(As + row * 40 + c * 8) = av;
      float4 bv = *(const float4*)(B + (long long)(n0 + row) * K + k0 + c * 8);
      *(float4*)(Bs + row * 40 + c * 8) = bv;
    }
    __syncthreads();
    bf16x8 af[4], bfr[4];
#pragma unroll
    for (int i = 0; i < 4; ++i) {
      af[i]  = *(const bf16x8*)(As + (mw + i * 16 + fr) * 40 + fq * 8);
      bfr[i] = *(const bf16x8*)(Bs + (nw + i * 16 + fr) * 40 + fq * 8);
    }
#pragma unroll
    for (int i = 0; i < 4; ++i)
#pragma unroll
      for (int j = 0; j < 4; ++j)
        acc[i][j] = __builtin_amdgcn_mfma_f32_16x16x32_bf16(
            af[i], bfr[j], acc[i][j], 0, 0, 0);
  }
#pragma unroll
  for (int i = 0; i < 4; ++i) {
#pragma unroll
    for (int j = 0; j < 4; ++j) {
      int n = n0 + nw + j * 16 + fr;
      float bv = bias[n];
#pragma unroll
      for (int q = 0; q < 4; ++q) {
        int m = m0 + mw + i * 16 + fq * 4 + q;
        if constexpr (BF16OUT)
          ((ushort*)Cv)[(long long)m * N + n] = f2bf(acc[i][j][q] + bv);
        else
          ((float*)Cv)[(long long)m * N + n] = acc[i][j][q] + bv;
      }
    }
  }
}

// ---------------- MFMA rel-shift attention (tile-local window) ---------------
// Grid (T/64, B*H), 256 threads = 4 waves; wave w owns score rows 16w..16w+15.
// Per s-tile: stage K(64) and R-window(128 rows, g = 960+s0-t0+j), compute
//   AC = (q+rwb)�k^T   (8 MFMA)
//   W[t'][j] = (q[t']+rrb)�rwin[j], t'=0..64, j=0..127 (16+4 MFMA) -> LDS bf16
//   scores: sc = AC + W[dt+sel][63+delta], sel=(delta>thr); diag forced 0
//   online softmax -> P -> LDS; V^T -> LDS; PV (8 MFMA).
// No LDS region aliasing in the main loop; 3 barriers/tile.
__global__ __launch_bounds__(256) void attn4_kernel(
    const ushort* __restrict__ qkv, const ushort* __restrict__ rb,
    const float* __restrict__ rwb, const float* __restrict__ rrb,
    ushort* __restrict__ outb) {
  __shared__ __align__(16) ushort Kls[64 * 72];
  __shared__ __align__(16) ushort Rls[128 * 72];
  __shared__ __align__(16) ushort Pls[64 * 72];
  __shared__ __align__(16) ushort Vls[64 * 72];
  __shared__ __align__(16) ushort Wb[65][132];

  const int t0 = blockIdx.x * 64;
  const int b = blockIdx.y >> 4, h = blockIdx.y & 15;
  const int tid = threadIdx.x;
  const int l = tid & 63, w = tid >> 6;
  const int fr = l & 15, fq = l >> 4;
  const int srow = tid >> 2;        // 0..63
  const int sd0 = (tid & 3) * 16;   // 0,16,32,48

  // ---- prologue A: q+rwb -> Kls(64x72); read AC A-frags ----
  {
    long long qo = ((long long)(t0 + srow) * B_SZ + b) * E3 + h * 64 + sd0;
#pragma unroll
    for (int j = 0; j < 16; ++j)
      Kls[srow * 72 + sd0 + j] =
          f2bf(bf2f(qkv[qo + j]) + rwb[h * 64 + sd0 + j]);
  }
  __syncthreads();
  const bf16x8 acA0 = *(const bf16x8*)(Kls + (16 * w + fr) * 72 + fq * 8);
  const bf16x8 acA1 = *(const bf16x8*)(Kls + (16 * w + fr) * 72 + fq * 8 + 32);
  __syncthreads();
  // ---- prologue B: q+rrb rows 0..79 -> Rls; read W A-frags ----
  {
    long long qo = ((long long)(t0 + srow) * B_SZ + b) * E3 + h * 64 + sd0;
#pragma unroll
    for (int j = 0; j < 16; ++j)
      Rls[srow * 72 + sd0 + j] =
          f2bf(bf2f(qkv[qo + j]) + rrb[h * 64 + sd0 + j]);
  }
  if (tid < 64) {
    int row = 64 + (tid >> 2);
    int d0 = (tid & 3) * 16;
    if (row == 64 && t0 + 64 < T_SEQ) {
      long long qo = ((long long)(t0 + 64) * B_SZ + b) * E3 + h * 64 + d0;
#pragma unroll
      for (int j = 0; j < 16; ++j)
        Rls[row * 72 + d0 + j] =
            f2bf(bf2f(qkv[qo + j]) + rrb[h * 64 + d0 + j]);
    } else {
#pragma unroll
      for (int j = 0; j < 16; ++j) Rls[row * 72 + d0 + j] = 0;
    }
  }
  __syncthreads();
  const bf16x8 aW0  = *(const bf16x8*)(Rls + (16 * w + fr) * 72 + fq * 8);
  const bf16x8 aW1  = *(const bf16x8*)(Rls + (16 * w + fr) * 72 + fq * 8 + 32);
  const bf16x8 aW40 = *(const bf16x8*)(Rls + (64 + fr) * 72 + fq * 8);
  const bf16x8 aW41 = *(const bf16x8*)(Rls + (64 + fr) * 72 + fq * 8 + 32);
  __syncthreads();  // frag reads done before tile-0 staging overwrites

  float m_r[4], l_r[4];
  f32x4 oacc[4];
#pragma unroll
  for (int q = 0; q < 4; ++q) { m_r[q] = -1e30f; l_r[q] = 0.f; }
#pragma unroll
  for (int c = 0; c < 4; ++c)
#pragma unroll
    for (int q = 0; q < 4; ++q) oacc[c][q] = 0.f;

  for (int ti = 0; ti < 16; ++ti) {
    const int s0 = ti * 64;
    // stage K tile [s][d]
    {
      long long ko =
          ((long long)(s0 + srow) * B_SZ + b) * E3 + E_DIM + h * 64 + sd0;
      u16x8 k0 = *(const u16x8*)(qkv + ko);
      u16x8 k1 = *(const u16x8*)(qkv + ko + 8);
      *(u16x8*)(Kls + srow * 72 + sd0) = k0;
      *(u16x8*)(Kls + srow * 72 + sd0 + 8) = k1;
    }
    // stage R window rows srow, srow+64; g = g0+row; g==1024 row -> zeros
    const int g0 = 960 + s0 - t0;
#pragma unroll
    for (int half = 0; half < 2; ++half) {
      int row = srow + half * 64;
      int g = g0 + row;
      int cr = (g <= 1023) ? g : g - 1025;
      u16x8 r0, r1;
#pragma unroll
      for (int j = 0; j < 8; ++j) { r0[j] = 0; r1[j] = 0; }
      if (cr >= 0 && cr < 1024) {
        long long ro = (long long)cr * E_DIM + h * 64 + sd0;
        r0 = *(const u16x8*)(rb + ro);
        r1 = *(const u16x8*)(rb + ro + 8);
      }
      *(u16x8*)(Rls + row * 72 + sd0) = r0;
      *(u16x8*)(Rls + row * 72 + sd0 + 8) = r1;
    }
    __syncthreads();  // B_a

    // AC GEMM
    f32x4 accAC[4];
#pragma unroll
    for (int c = 0; c < 4; ++c)
#pragma unroll
      for (int q = 0; q < 4; ++q) accAC[c][q] = 0.f;
#pragma unroll
    for (int cf = 0; cf < 4; ++cf) {
      const ushort* kp = Kls + (16 * cf + fr) * 72 + fq * 8;
      bf16x8 b0 = *(const bf16x8*)kp;
      bf16x8 b1 = *(const bf16x8*)(kp + 32);
      accAC[cf] = __builtin_amdgcn_mfma_f32_16x16x32_bf16(acA0, b0, accAC[cf], 0, 0, 0);
      accAC[cf] = __builtin_amdgcn_mfma_f32_16x16x32_bf16(acA1, b1, accAC[cf], 0, 0, 0);
    }
    // W GEMM: rows 16w..16w+15 x 128 window cols
#pragma unroll
    for (int cb = 0; cb < 8; ++cb) {
      const ushort* rp = Rls + (16 * cb + fr) * 72 + fq * 8;
      bf16x8 r0 = *(const bf16x8*)rp;
      bf16x8 r1 = *(const bf16x8*)(rp + 32);
      f32x4 acw;
#pragma unroll
      for (int q = 0; q < 4; ++q) acw[q] = 0.f;
      acw = __builtin_amdgcn_mfma_f32_16x16x32_bf16(aW0, r0, acw, 0, 0, 0);
      acw = __builtin_amdgcn_mfma_f32_16x16x32_bf16(aW1, r1, acw, 0, 0, 0);
#pragma unroll
      for (int q = 0; q < 4; ++q)
        Wb[16 * w + 4 * fq + q][16 * cb + fr] = f2bf(acw[q]);
    }
    // W row 64 (q[t0+64]): wave w covers col-blocks 2w, 2w+1
#pragma unroll
    for (int c = 0; c < 2; ++c) {
      const ushort* rp = Rls + (16 * (2 * w + c) + fr) * 72 + fq * 8;
      bf16x8 r0 = *(const bf16x8*)rp;
      bf16x8 r1 = *(const bf16x8*)(rp + 32);
      f32x4 acw;
#pragma unroll
      for (int q = 0; q < 4; ++q) acw[q] = 0.f;
      acw = __builtin_amdgcn_mfma_f32_16x16x32_bf16(aW40, r0, acw, 0, 0, 0);
      acw = __builtin_amdgcn_mfma_f32_16x16x32_bf16(aW41, r1, acw, 0, 0, 0);
      if (fq == 0) Wb[64][16 * (2 * w + c) + fr] = f2bf(acw[0]);
    }
    __syncthreads();  // B_b

    // assemble scores + online softmax
    const int thr = t0 - s0;
    float pvv[4][4];
#pragma unroll
    for (int q = 0; q < 4; ++q) {
      const int dt_ = 16 * w + 4 * fq + q;
      float sc[4];
#pragma unroll
      for (int cf = 0; cf < 4; ++cf) {
        const int delta = 16 * cf + fr - dt_;
        const int sel = (delta > thr) ? 1 : 0;
        float Wv =
            (delta == thr + 1) ? 0.f : bf2f(Wb[dt_ + sel][63 + delta]);
        sc[cf] = (accAC[cf][q] + Wv) * 0.125f;
      }
      float mt = fmaxf(fmaxf(sc[0], sc[1]), fmaxf(sc[2], sc[3]));
#pragma unroll
      for (int off = 8; off >= 1; off >>= 1)
        mt = fmaxf(mt, __shfl_xor(mt, off));
      float mnew = fmaxf(m_r[q], mt);
      float alpha = __expf(m_r[q] - mnew);
      m_r[q] = mnew;
      float ps = 0.f;
#pragma unroll
      for (int cf = 0; cf < 4; ++cf) {
        pvv[q][cf] = __expf(sc[cf] - mnew);
        ps += pvv[q][cf];
      }
#pragma unroll
      for (int off = 8; off >= 1; off >>= 1) ps += __shfl_xor(ps, off);
      l_r[q] = l_r[q] * alpha + ps;
#pragma unroll
      for (int cfd = 0; cfd < 4; ++cfd) oacc[cfd][q] *= alpha;
    }
    // write P [t][s] and V^T [d][s]
#pragma unroll
    for (int q = 0; q < 4; ++q)
#pragma unroll
      for (int cf = 0; cf < 4; ++cf)
        Pls[(16 * w + 4 * fq + q) * 72 + 16 * cf + fr] = f2bf(pvv[q][cf]);
    {
      long long vo =
          ((long long)(s0 + srow) * B_SZ + b) * E3 + 2 * E_DIM + h * 64 + sd0;
      u16x8 v0 = *(const u16x8*)(qkv + vo);
      u16x8 v1 = *(const u16x8*)(qkv + vo + 8);
#pragma unroll
      for (int j = 0; j < 8; ++j) {
        Vls[(sd0 + j) * 72 + srow] = (ushort)v0[j];
        Vls[(sd0 + 8 + j) * 72 + srow] = (ushort)v1[j];
      }
    }
    __syncthreads();  // B_c

    // PV GEMM
#pragma unroll
    for (int ks = 0; ks < 2; ++ks) {
      bf16x8 aP = *(const bf16x8*)(Pls + (16 * w + fr) * 72 + fq * 8 + 32 * ks);
#pragma unroll
      for (int cfd = 0; cfd < 4; ++cfd) {
        bf16x8 bV =
            *(const bf16x8*)(Vls + (16 * cfd + fr) * 72 + fq * 8 + 32 * ks);
        oacc[cfd] =
            __builtin_amdgcn_mfma_f32_16x16x32_bf16(aP, bV, oacc[cfd], 0, 0, 0);
      }
    }
  }

#pragma unroll
  for (int q = 0; q < 4; ++q) {
    float inv = 1.f / l_r[q];
    int t = t0 + 16 * w + 4 * fq + q;
#pragma unroll
    for (int cfd = 0; cfd < 4; ++cfd)
      outb[((long long)t * B_SZ + b) * E_DIM + h * 64 + 16 * cfd + fr] =
          f2bf(oacc[cfd][q] * inv);
  }
}

// ---------------- launch ----------------
extern "C" void kernel_launch(void* const* d_in, const int* in_sizes, int n_in,
                              void* d_out, int out_size, void* d_ws,
                              size_t ws_size, hipStream_t stream) {
  const float* input = (const float*)d_in[0];
  const float* pos   = (const float*)d_in[1];
  const int*   idx   = (const int*)d_in[2];
  const float* in_w  = (const float*)d_in[3];
  const float* in_b  = (const float*)d_in[4];
  const float* out_w = (const float*)d_in[5];
  const float* out_b = (const float*)d_in[6];
  const float* pos_w = (const float*)d_in[7];
  const float* pos_b = (const float*)d_in[8];
  const float* r_i   = (const float*)d_in[9];
  const float* s_i   = (const float*)d_in[10];
  const float* r_p   = (const float*)d_in[11];
  const float* s_p   = (const float*)d_in[12];
  const float* r_o   = (const float*)d_in[13];
  const float* s_o   = (const float*)d_in[14];
  const float* rm_i  = (const float*)d_in[15];
  const float* sm_i  = (const float*)d_in[16];
  const float* rm_p  = (const float*)d_in[17];
  const float* sm_p  = (const float*)d_in[18];
  const float* rm_o  = (const float*)d_in[19];
  const float* sm_o  = (const float*)d_in[20];
  const float* rwb   = (const float*)d_in[21];
  const float* rrb   = (const float*)d_in[22];
  float* out = (float*)d_out;

  // workspace layout (bytes), ~46 MB total
  char* base = (char*)d_ws;
  ushort* qkvb  = (ushort*)(base);                        // 24MB bf16 [4096][3072]
  ushort* rbufb = (ushort*)(base + 24ll * 1024 * 1024);   //  2MB bf16 [1024][1024]
  ushort* Wi    = (ushort*)(base + 26ll * 1024 * 1024);   //  6MB
  ushort* Wp    = (ushort*)(base + 32ll * 1024 * 1024);   //  2MB
  ushort* Wo    = (ushort*)(base + 34ll * 1024 * 1024);   //  2MB
  ushort* ibf   = (ushort*)(base + 36ll * 1024 * 1024);   //  8MB bf16 [4096][1024]
  ushort* pbf   = (ushort*)(base + 44ll * 1024 * 1024);   //  2MB
  ushort* abf   = ibf;  // attn out aliases ibf (dead after qkv GEMM)

  cast_bf16_kernel<<<(T_SEQ * B_SZ * E_DIM / 4 + 255) / 256, 256, 0, stream>>>(
      input, ibf, (long long)T_SEQ * B_SZ * E_DIM / 4);
  cast_bf16_kernel<<<(T_SEQ * E_DIM / 4 + 255) / 256, 256, 0, stream>>>(
      pos, pbf, (long long)T_SEQ * E_DIM / 4);
  {
    long long n1 = (long long)E3 * E_DIM;
    factorize_kernel<<<(n1 + 255) / 256, 256, 0, stream>>>(
        in_w, rm_i, sm_i, r_i, s_i, idx, Wi, E3, E_DIM);
    long long n2 = (long long)E_DIM * E_DIM;
    factorize_kernel<<<(n2 + 255) / 256, 256, 0, stream>>>(
        pos_w, rm_p, sm_p, r_p, s_p, idx, Wp, E_DIM, E_DIM);
    factorize_kernel<<<(n2 + 255) / 256, 256, 0, stream>>>(
        out_w, rm_o, sm_o, r_o, s_o, idx, Wo, E_DIM, E_DIM);
  }
  // qkv (bf16) = input @ Wi^T + bias
  gemm_mfma_kernel<true><<<dim3(E3 / 128, (T_SEQ * B_SZ) / 128), 256, 0, stream>>>(
      ibf, Wi, in_b, qkvb, T_SEQ * B_SZ, E3, E_DIM);
  // rbuf (bf16) = pos @ Wp^T + bias
  gemm_mfma_kernel<true><<<dim3(E_DIM / 128, T_SEQ / 128), 256, 0, stream>>>(
      pbf, Wp, pos_b, rbufb, T_SEQ, E_DIM, E_DIM);
  // fused MFMA attention -> abf (bf16)
  attn4_kernel<<<dim3(T_SEQ / 64, B_SZ * H_DIM), 256, 0, stream>>>(
      qkvb, rbufb, rwb, rrb, abf);
  // out (f32) = attn @ Wo^T + bias
  gemm_mfma_kernel<false><<<dim3(E_DIM / 128, (T_SEQ * B_SZ) / 128), 256, 0, stream>>>(
      abf, Wo, out_b, out, T_SEQ * B_SZ, E_DIM, E_DIM);
}

// Round 7
// 277.482 us; speedup vs baseline: 8.8426x; 1.0041x over previous
//
#include <hip/hip_runtime.h>
#include <hip/hip_bf16.h>
#include <math.h>

#define E_DIM  1024
#define H_DIM  16
#define D_DIM  64
#define T_SEQ  1024
#define B_SZ   4
#define E3     3072
#define R_RANK 4

typedef __attribute__((ext_vector_type(8))) short bf16x8;
typedef __attribute__((ext_vector_type(8))) unsigned short u16x8;
typedef __attribute__((ext_vector_type(4))) float f32x4;

static __device__ __forceinline__ ushort f2bf(float x) {
  __hip_bfloat16 h = __float2bfloat16(x);
  return *(ushort*)&h;
}
static __device__ __forceinline__ float bf2f(ushort u) {
  unsigned int v = ((unsigned int)u) << 16;
  float f;
  __builtin_memcpy(&f, &v, 4);
  return f;
}

#define GLOAD_LDS16(g, l)                                                     \
  __builtin_amdgcn_global_load_lds(                                           \
      (const __attribute__((address_space(1))) void*)(g),                     \
      (__attribute__((address_space(3))) void*)(l), 16, 0, 0)

// ---------------- cast f32 -> bf16 ----------------
__global__ void cast_bf16_kernel(const float* __restrict__ in,
                                 ushort* __restrict__ out, long long n4) {
  long long i = (long long)blockIdx.x * blockDim.x + threadIdx.x;
  if (i >= n4) return;
  float4 v = *(const float4*)(in + i * 4);
  ushort4 o;
  o.x = f2bf(v.x); o.y = f2bf(v.y); o.z = f2bf(v.z); o.w = f2bf(v.w);
  *(ushort4*)(out + i * 4) = o;
}

// ---------------- weight factorization (emits bf16) ----------------
__global__ void factorize_kernel(const float* __restrict__ W,
                                 const float* __restrict__ rm,
                                 const float* __restrict__ sm,
                                 const float* __restrict__ r,
                                 const float* __restrict__ s,
                                 const int* __restrict__ idxp,
                                 ushort* __restrict__ out,
                                 int A, int Bc) {
  int idx = idxp[0];
  long long i = (long long)blockIdx.x * blockDim.x + threadIdx.x;
  long long total = (long long)A * Bc;
  if (i >= total) return;
  int a = (int)(i / Bc);
  int b = (int)(i % Bc);
  float acc = W[i] * rm[(long long)idx * A + a] * sm[(long long)idx * Bc + b];
#pragma unroll
  for (int k = 0; k < R_RANK; ++k) {
    acc += r[((long long)idx * R_RANK + k) * A + a] *
           s[((long long)idx * R_RANK + k) * Bc + b];
  }
  out[i] = f2bf(acc);
}

// ---------------- bf16 MFMA GEMM (m97-style): C = A * B^T + bias ------------
// 128x128 tile, BK=32, 4 waves. Linear LDS [128][32] (required by
// global_load_lds: dest = wave-uniform base + lane*16B). 2 barriers/K-step.
template <bool BF16OUT>
__global__ __launch_bounds__(256) void gemm_mfma_kernel(
    const ushort* __restrict__ A, const ushort* __restrict__ B,
    const float* __restrict__ bias, void* __restrict__ Cv,
    int M, int N, int K) {
  __shared__ __align__(16) ushort As[128 * 32];
  __shared__ __align__(16) ushort Bs[128 * 32];
  const int tid = threadIdx.x;
  const int l = tid & 63, w = tid >> 6;
  const int m0 = blockIdx.y * 128, n0 = blockIdx.x * 128;
  const int mw = (w >> 1) * 64, nw = (w & 1) * 64;
  const int fr = l & 15, fq = l >> 4;
  const int lrow = l >> 2;         // 0..15 row within 16-row chunk
  const int lk = (l & 3) * 8;      // k-offset in ushorts (16B)

  f32x4 acc[4][4];
#pragma unroll
  for (int i = 0; i < 4; ++i)
#pragma unroll
    for (int j = 0; j < 4; ++j)
#pragma unroll
      for (int q = 0; q < 4; ++q) acc[i][j][q] = 0.f;

  for (int k0 = 0; k0 < K; k0 += 32) {
    __syncthreads();  // previous frag reads complete
#pragma unroll
    for (int p = 0; p < 2; ++p) {
      int row = w * 32 + p * 16;  // wave-uniform base row
      GLOAD_LDS16(A + (long long)(m0 + row + lrow) * K + k0 + lk,
                  As + row * 32);
      GLOAD_LDS16(B + (long long)(n0 + row + lrow) * K + k0 + lk,
                  Bs + row * 32);
    }
    __syncthreads();  // drains vmcnt before any LDS read
    bf16x8 af[4], bfr[4];
#pragma unroll
    for (int i = 0; i < 4; ++i) {
      af[i]  = *(const bf16x8*)(As + (mw + i * 16 + fr) * 32 + fq * 8);
      bfr[i] = *(const bf16x8*)(Bs + (nw + i * 16 + fr) * 32 + fq * 8);
    }
#pragma unroll
    for (int i = 0; i < 4; ++i)
#pragma unroll
      for (int j = 0; j < 4; ++j)
        acc[i][j] = __builtin_amdgcn_mfma_f32_16x16x32_bf16(
            af[i], bfr[j], acc[i][j], 0, 0, 0);
  }
#pragma unroll
  for (int i = 0; i < 4; ++i) {
#pragma unroll
    for (int j = 0; j < 4; ++j) {
      int n = n0 + nw + j * 16 + fr;
      float bv = bias[n];
#pragma unroll
      for (int q = 0; q < 4; ++q) {
        int m = m0 + mw + i * 16 + fq * 4 + q;
        if constexpr (BF16OUT)
          ((ushort*)Cv)[(long long)m * N + n] = f2bf(acc[i][j][q] + bv);
        else
          ((float*)Cv)[(long long)m * N + n] = acc[i][j][q] + bv;
      }
    }
  }
}

// ---------------- MFMA rel-shift attention v5 --------------------------------
// Same algorithm as the passing attn4 (tile-local 128-row R window), plus:
//  - P/V aliased into Rls (dead after B_b) -> LDS 63.5KB -> 44.8KB (3 blk/CU)
//  - 4th barrier at loop end protects PV reads from next tile's staging
//  - XOR bank swizzles (matched on write+read, 8-ushort granularity):
//      K/R/P: idx ^= (row&8)?8:0   V: idx ^= ((d>>3)&7)<<3
static __device__ __forceinline__ int kri(int row, int d) {
  return (row * 72 + d) ^ ((row & 8) ? 8 : 0);
}
static __device__ __forceinline__ int vdi(int d, int s) {
  return 64 * 72 + ((d * 72 + s) ^ (((d >> 3) & 7) << 3));
}

__global__ __launch_bounds__(256) void attn5_kernel(
    const ushort* __restrict__ qkv, const ushort* __restrict__ rb,
    const float* __restrict__ rwb, const float* __restrict__ rrb,
    ushort* __restrict__ outb) {
  __shared__ __align__(16) ushort Kls[64 * 72];    // K tile / qw (prologue)
  __shared__ __align__(16) ushort Rls[128 * 72];   // R window / qr / P+V
  __shared__ __align__(16) ushort Wb[65][132];

  const int t0 = blockIdx.x * 64;
  const int b = blockIdx.y >> 4, h = blockIdx.y & 15;
  const int tid = threadIdx.x;
  const int l = tid & 63, w = tid >> 6;
  const int fr = l & 15, fq = l >> 4;
  const int srow = tid >> 2;        // 0..63
  const int sd0 = (tid & 3) * 16;   // 0,16,32,48

  // ---- prologue A: q+rwb -> Kls; read AC A-frags ----
  {
    long long qo = ((long long)(t0 + srow) * B_SZ + b) * E3 + h * 64 + sd0;
#pragma unroll
    for (int j = 0; j < 16; ++j)
      Kls[kri(srow, sd0 + j)] =
          f2bf(bf2f(qkv[qo + j]) + rwb[h * 64 + sd0 + j]);
  }
  __syncthreads();
  const bf16x8 acA0 = *(const bf16x8*)(Kls + kri(16 * w + fr, fq * 8));
  const bf16x8 acA1 = *(const bf16x8*)(Kls + kri(16 * w + fr, fq * 8 + 32));
  __syncthreads();
  // ---- prologue B: q+rrb rows 0..79 -> Rls; read W A-frags ----
  {
    long long qo = ((long long)(t0 + srow) * B_SZ + b) * E3 + h * 64 + sd0;
#pragma unroll
    for (int j = 0; j < 16; ++j)
      Rls[kri(srow, sd0 + j)] =
          f2bf(bf2f(qkv[qo + j]) + rrb[h * 64 + sd0 + j]);
  }
  if (tid < 64) {
    int row = 64 + (tid >> 2);
    int d0 = (tid & 3) * 16;
    if (row == 64 && t0 + 64 < T_SEQ) {
      long long qo = ((long long)(t0 + 64) * B_SZ + b) * E3 + h * 64 + d0;
#pragma unroll
      for (int j = 0; j < 16; ++j)
        Rls[kri(row, d0 + j)] =
            f2bf(bf2f(qkv[qo + j]) + rrb[h * 64 + d0 + j]);
    } else {
#pragma unroll
      for (int j = 0; j < 16; ++j) Rls[kri(row, d0 + j)] = 0;
    }
  }
  __syncthreads();
  const bf16x8 aW0  = *(const bf16x8*)(Rls + kri(16 * w + fr, fq * 8));
  const bf16x8 aW1  = *(const bf16x8*)(Rls + kri(16 * w + fr, fq * 8 + 32));
  const bf16x8 aW40 = *(const bf16x8*)(Rls + kri(64 + fr, fq * 8));
  const bf16x8 aW41 = *(const bf16x8*)(Rls + kri(64 + fr, fq * 8 + 32));
  __syncthreads();  // frag reads done before tile-0 staging overwrites

  float m_r[4], l_r[4];
  f32x4 oacc[4];
#pragma unroll
  for (int q = 0; q < 4; ++q) { m_r[q] = -1e30f; l_r[q] = 0.f; }
#pragma unroll
  for (int c = 0; c < 4; ++c)
#pragma unroll
    for (int q = 0; q < 4; ++q) oacc[c][q] = 0.f;

  for (int ti = 0; ti < 16; ++ti) {
    const int s0 = ti * 64;
    // stage K tile [s][d]
    {
      long long ko =
          ((long long)(s0 + srow) * B_SZ + b) * E3 + E_DIM + h * 64 + sd0;
      u16x8 k0 = *(const u16x8*)(qkv + ko);
      u16x8 k1 = *(const u16x8*)(qkv + ko + 8);
      *(u16x8*)(Kls + kri(srow, sd0)) = k0;
      *(u16x8*)(Kls + kri(srow, sd0 + 8)) = k1;
    }
    // stage R window rows srow, srow+64; g = g0+row; g==1024 row -> zeros
    const int g0 = 960 + s0 - t0;
#pragma unroll
    for (int half = 0; half < 2; ++half) {
      int row = srow + half * 64;
      int g = g0 + row;
      int cr = (g <= 1023) ? g : g - 1025;
      u16x8 r0, r1;
#pragma unroll
      for (int j = 0; j < 8; ++j) { r0[j] = 0; r1[j] = 0; }
      if (cr >= 0 && cr < 1024) {
        long long ro = (long long)cr * E_DIM + h * 64 + sd0;
        r0 = *(const u16x8*)(rb + ro);
        r1 = *(const u16x8*)(rb + ro + 8);
      }
      *(u16x8*)(Rls + kri(row, sd0)) = r0;
      *(u16x8*)(Rls + kri(row, sd0 + 8)) = r1;
    }
    __syncthreads();  // B_a

    // AC GEMM
    f32x4 accAC[4];
#pragma unroll
    for (int c = 0; c < 4; ++c)
#pragma unroll
      for (int q = 0; q < 4; ++q) accAC[c][q] = 0.f;
#pragma unroll
    for (int cf = 0; cf < 4; ++cf) {
      bf16x8 b0 = *(const bf16x8*)(Kls + kri(16 * cf + fr, fq * 8));
      bf16x8 b1 = *(const bf16x8*)(Kls + kri(16 * cf + fr, fq * 8 + 32));
      accAC[cf] = __builtin_amdgcn_mfma_f32_16x16x32_bf16(acA0, b0, accAC[cf], 0, 0, 0);
      accAC[cf] = __builtin_amdgcn_mfma_f32_16x16x32_bf16(acA1, b1, accAC[cf], 0, 0, 0);
    }
    // W GEMM: rows 16w..16w+15 x 128 window cols
#pragma unroll
    for (int cb = 0; cb < 8; ++cb) {
      bf16x8 r0 = *(const bf16x8*)(Rls + kri(16 * cb + fr, fq * 8));
      bf16x8 r1 = *(const bf16x8*)(Rls + kri(16 * cb + fr, fq * 8 + 32));
      f32x4 acw;
#pragma unroll
      for (int q = 0; q < 4; ++q) acw[q] = 0.f;
      acw = __builtin_amdgcn_mfma_f32_16x16x32_bf16(aW0, r0, acw, 0, 0, 0);
      acw = __builtin_amdgcn_mfma_f32_16x16x32_bf16(aW1, r1, acw, 0, 0, 0);
#pragma unroll
      for (int q = 0; q < 4; ++q)
        Wb[16 * w + 4 * fq + q][16 * cb + fr] = f2bf(acw[q]);
    }
    // W row 64 (q[t0+64]): wave w covers col-blocks 2w, 2w+1
#pragma unroll
    for (int c = 0; c < 2; ++c) {
      bf16x8 r0 = *(const bf16x8*)(Rls + kri(16 * (2 * w + c) + fr, fq * 8));
      bf16x8 r1 = *(const bf16x8*)(Rls + kri(16 * (2 * w + c) + fr, fq * 8 + 32));
      f32x4 acw;
#pragma unroll
      for (int q = 0; q < 4; ++q) acw[q] = 0.f;
      acw = __builtin_amdgcn_mfma_f32_16x16x32_bf16(aW40, r0, acw, 0, 0, 0);
      acw = __builtin_amdgcn_mfma_f32_16x16x32_bf16(aW41, r1, acw, 0, 0, 0);
      if (fq == 0) Wb[64][16 * (2 * w + c) + fr] = f2bf(acw[0]);
    }
    __syncthreads();  // B_b  (K/R reads done; P/V may now overwrite Rls)

    // assemble scores + online softmax
    const int thr = t0 - s0;
    float pvv[4][4];
#pragma unroll
    for (int q = 0; q < 4; ++q) {
      const int dt_ = 16 * w + 4 * fq + q;
      float sc[4];
#pragma unroll
      for (int cf = 0; cf < 4; ++cf) {
        const int delta = 16 * cf + fr - dt_;
        const int sel = (delta > thr) ? 1 : 0;
        float Wv =
            (delta == thr + 1) ? 0.f : bf2f(Wb[dt_ + sel][63 + delta]);
        sc[cf] = (accAC[cf][q] + Wv) * 0.125f;
      }
      float mt = fmaxf(fmaxf(sc[0], sc[1]), fmaxf(sc[2], sc[3]));
#pragma unroll
      for (int off = 8; off >= 1; off >>= 1)
        mt = fmaxf(mt, __shfl_xor(mt, off));
      float mnew = fmaxf(m_r[q], mt);
      float alpha = __expf(m_r[q] - mnew);
      m_r[q] = mnew;
      float ps = 0.f;
#pragma unroll
      for (int cf = 0; cf < 4; ++cf) {
        pvv[q][cf] = __expf(sc[cf] - mnew);
        ps += pvv[q][cf];
      }
#pragma unroll
      for (int off = 8; off >= 1; off >>= 1) ps += __shfl_xor(ps, off);
      l_r[q] = l_r[q] * alpha + ps;
#pragma unroll
      for (int cfd = 0; cfd < 4; ++cfd) oacc[cfd][q] *= alpha;
    }
    // write P [t][s] into Rls rows 0..63; V^T [d][s] into Rls rows 64..127
#pragma unroll
    for (int q = 0; q < 4; ++q)
#pragma unroll
      for (int cf = 0; cf < 4; ++cf)
        Rls[kri(16 * w + 4 * fq + q, 16 * cf + fr)] = f2bf(pvv[q][cf]);
    {
      long long vo =
          ((long long)(s0 + srow) * B_SZ + b) * E3 + 2 * E_DIM + h * 64 + sd0;
      u16x8 v0 = *(const u16x8*)(qkv + vo);
      u16x8 v1 = *(const u16x8*)(qkv + vo + 8);
#pragma unroll
      for (int j = 0; j < 8; ++j) {
        Rls[vdi(sd0 + j, srow)] = (ushort)v0[j];
        Rls[vdi(sd0 + 8 + j, srow)] = (ushort)v1[j];
      }
    }
    __syncthreads();  // B_c

    // PV GEMM
#pragma unroll
    for (int ks = 0; ks < 2; ++ks) {
      bf16x8 aP = *(const bf16x8*)(Rls + kri(16 * w + fr, fq * 8 + 32 * ks));
#pragma unroll
      for (int cfd = 0; cfd < 4; ++cfd) {
        bf16x8 bV = *(const bf16x8*)(Rls + vdi(16 * cfd + fr, fq * 8 + 32 * ks));
        oacc[cfd] =
            __builtin_amdgcn_mfma_f32_16x16x32_bf16(aP, bV, oacc[cfd], 0, 0, 0);
      }
    }
    __syncthreads();  // B_d: PV reads done before next tile's staging
  }

#pragma unroll
  for (int q = 0; q < 4; ++q) {
    float inv = 1.f / l_r[q];
    int t = t0 + 16 * w + 4 * fq + q;
#pragma unroll
    for (int cfd = 0; cfd < 4; ++cfd)
      outb[((long long)t * B_SZ + b) * E_DIM + h * 64 + 16 * cfd + fr] =
          f2bf(oacc[cfd][q] * inv);
  }
}

// ---------------- launch ----------------
extern "C" void kernel_launch(void* const* d_in, const int* in_sizes, int n_in,
                              void* d_out, int out_size, void* d_ws,
                              size_t ws_size, hipStream_t stream) {
  const float* input = (const float*)d_in[0];
  const float* pos   = (const float*)d_in[1];
  const int*   idx   = (const int*)d_in[2];
  const float* in_w  = (const float*)d_in[3];
  const float* in_b  = (const float*)d_in[4];
  const float* out_w = (const float*)d_in[5];
  const float* out_b = (const float*)d_in[6];
  const float* pos_w = (const float*)d_in[7];
  const float* pos_b = (const float*)d_in[8];
  const float* r_i   = (const float*)d_in[9];
  const float* s_i   = (const float*)d_in[10];
  const float* r_p   = (const float*)d_in[11];
  const float* s_p   = (const float*)d_in[12];
  const float* r_o   = (const float*)d_in[13];
  const float* s_o   = (const float*)d_in[14];
  const float* rm_i  = (const float*)d_in[15];
  const float* sm_i  = (const float*)d_in[16];
  const float* rm_p  = (const float*)d_in[17];
  const float* sm_p  = (const float*)d_in[18];
  const float* rm_o  = (const float*)d_in[19];
  const float* sm_o  = (const float*)d_in[20];
  const float* rwb   = (const float*)d_in[21];
  const float* rrb   = (const float*)d_in[22];
  float* out = (float*)d_out;

  // workspace layout (bytes), ~46 MB total
  char* base = (char*)d_ws;
  ushort* qkvb  = (ushort*)(base);                        // 24MB bf16 [4096][3072]
  ushort* rbufb = (ushort*)(base + 24ll * 1024 * 1024);   //  2MB bf16 [1024][1024]
  ushort* Wi    = (ushort*)(base + 26ll * 1024 * 1024);   //  6MB
  ushort* Wp    = (ushort*)(base + 32ll * 1024 * 1024);   //  2MB
  ushort* Wo    = (ushort*)(base + 34ll * 1024 * 1024);   //  2MB
  ushort* ibf   = (ushort*)(base + 36ll * 1024 * 1024);   //  8MB bf16 [4096][1024]
  ushort* pbf   = (ushort*)(base + 44ll * 1024 * 1024);   //  2MB
  ushort* abf   = ibf;  // attn out aliases ibf (dead after qkv GEMM)

  cast_bf16_kernel<<<(T_SEQ * B_SZ * E_DIM / 4 + 255) / 256, 256, 0, stream>>>(
      input, ibf, (long long)T_SEQ * B_SZ * E_DIM / 4);
  cast_bf16_kernel<<<(T_SEQ * E_DIM / 4 + 255) / 256, 256, 0, stream>>>(
      pos, pbf, (long long)T_SEQ * E_DIM / 4);
  {
    long long n1 = (long long)E3 * E_DIM;
    factorize_kernel<<<(n1 + 255) / 256, 256, 0, stream>>>(
        in_w, rm_i, sm_i, r_i, s_i, idx, Wi, E3, E_DIM);
    long long n2 = (long long)E_DIM * E_DIM;
    factorize_kernel<<<(n2 + 255) / 256, 256, 0, stream>>>(
        pos_w, rm_p, sm_p, r_p, s_p, idx, Wp, E_DIM, E_DIM);
    factorize_kernel<<<(n2 + 255) / 256, 256, 0, stream>>>(
        out_w, rm_o, sm_o, r_o, s_o, idx, Wo, E_DIM, E_DIM);
  }
  // qkv (bf16) = input @ Wi^T + bias
  gemm_mfma_kernel<true><<<dim3(E3 / 128, (T_SEQ * B_SZ) / 128), 256, 0, stream>>>(
      ibf, Wi, in_b, qkvb, T_SEQ * B_SZ, E3, E_DIM);
  // rbuf (bf16) = pos @ Wp^T + bias
  gemm_mfma_kernel<true><<<dim3(E_DIM / 128, T_SEQ / 128), 256, 0, stream>>>(
      pbf, Wp, pos_b, rbufb, T_SEQ, E_DIM, E_DIM);
  // fused MFMA attention -> abf (bf16)
  attn5_kernel<<<dim3(T_SEQ / 64, B_SZ * H_DIM), 256, 0, stream>>>(
      qkvb, rbufb, rwb, rrb, abf);
  // out (f32) = attn @ Wo^T + bias
  gemm_mfma_kernel<false><<<dim3(E_DIM / 128, (T_SEQ * B_SZ) / 128), 256, 0, stream>>>(
      abf, Wo, out_b, out, T_SEQ * B_SZ, E_DIM, E_DIM);
}

// Round 8
// 238.393 us; speedup vs baseline: 10.2925x; 1.1640x over previous
//
#include <hip/hip_runtime.h>
#include <hip/hip_bf16.h>
#include <math.h>

#define E_DIM  1024
#define H_DIM  16
#define D_DIM  64
#define T_SEQ  1024
#define B_SZ   4
#define E3     3072
#define R_RANK 4

typedef __attribute__((ext_vector_type(8))) short bf16x8;
typedef __attribute__((ext_vector_type(8))) unsigned short u16x8;
typedef __attribute__((ext_vector_type(4))) float f32x4;

static __device__ __forceinline__ ushort f2bf(float x) {
  __hip_bfloat16 h = __float2bfloat16(x);
  return *(ushort*)&h;
}
static __device__ __forceinline__ float bf2f(ushort u) {
  unsigned int v = ((unsigned int)u) << 16;
  float f;
  __builtin_memcpy(&f, &v, 4);
  return f;
}

// DPP row-rotate fold (16-lane row) — VALU pipe, replaces ds_swizzle shuffles.
template <int CTRL>
static __device__ __forceinline__ float dpp_rot(float x) {
  int r = __builtin_amdgcn_update_dpp(0, __builtin_bit_cast(int, x), CTRL,
                                      0xf, 0xf, true);
  return __builtin_bit_cast(float, r);
}
static __device__ __forceinline__ float row16_max(float x) {
  x = fmaxf(x, dpp_rot<0x128>(x));  // ror 8
  x = fmaxf(x, dpp_rot<0x124>(x));  // ror 4
  x = fmaxf(x, dpp_rot<0x122>(x));  // ror 2
  x = fmaxf(x, dpp_rot<0x121>(x));  // ror 1
  return x;
}
static __device__ __forceinline__ float row16_sum(float x) {
  x += dpp_rot<0x128>(x);
  x += dpp_rot<0x124>(x);
  x += dpp_rot<0x122>(x);
  x += dpp_rot<0x121>(x);
  return x;
}

#define GLOAD_LDS16(g, l)                                                     \
  __builtin_amdgcn_global_load_lds(                                           \
      (const __attribute__((address_space(1))) void*)(g),                     \
      (__attribute__((address_space(3))) void*)(l), 16, 0, 0)

// ---------------- cast f32 -> bf16 ----------------
__global__ void cast_bf16_kernel(const float* __restrict__ in,
                                 ushort* __restrict__ out, long long n4) {
  long long i = (long long)blockIdx.x * blockDim.x + threadIdx.x;
  if (i >= n4) return;
  float4 v = *(const float4*)(in + i * 4);
  ushort4 o;
  o.x = f2bf(v.x); o.y = f2bf(v.y); o.z = f2bf(v.z); o.w = f2bf(v.w);
  *(ushort4*)(out + i * 4) = o;
}

// ---------------- weight factorization (emits bf16) ----------------
__global__ void factorize_kernel(const float* __restrict__ W,
                                 const float* __restrict__ rm,
                                 const float* __restrict__ sm,
                                 const float* __restrict__ r,
                                 const float* __restrict__ s,
                                 const int* __restrict__ idxp,
                                 ushort* __restrict__ out,
                                 int A, int Bc) {
  int idx = idxp[0];
  long long i = (long long)blockIdx.x * blockDim.x + threadIdx.x;
  long long total = (long long)A * Bc;
  if (i >= total) return;
  int a = (int)(i / Bc);
  int b = (int)(i % Bc);
  float acc = W[i] * rm[(long long)idx * A + a] * sm[(long long)idx * Bc + b];
#pragma unroll
  for (int k = 0; k < R_RANK; ++k) {
    acc += r[((long long)idx * R_RANK + k) * A + a] *
           s[((long long)idx * R_RANK + k) * Bc + b];
  }
  out[i] = f2bf(acc);
}

// ---------------- bf16 MFMA GEMM (m97-style): C = A * B^T + bias ------------
template <bool BF16OUT>
__global__ __launch_bounds__(256) void gemm_mfma_kernel(
    const ushort* __restrict__ A, const ushort* __restrict__ B,
    const float* __restrict__ bias, void* __restrict__ Cv,
    int M, int N, int K) {
  __shared__ __align__(16) ushort As[128 * 32];
  __shared__ __align__(16) ushort Bs[128 * 32];
  const int tid = threadIdx.x;
  const int l = tid & 63, w = tid >> 6;
  const int m0 = blockIdx.y * 128, n0 = blockIdx.x * 128;
  const int mw = (w >> 1) * 64, nw = (w & 1) * 64;
  const int fr = l & 15, fq = l >> 4;
  const int lrow = l >> 2;
  const int lk = (l & 3) * 8;

  f32x4 acc[4][4];
#pragma unroll
  for (int i = 0; i < 4; ++i)
#pragma unroll
    for (int j = 0; j < 4; ++j)
#pragma unroll
      for (int q = 0; q < 4; ++q) acc[i][j][q] = 0.f;

  for (int k0 = 0; k0 < K; k0 += 32) {
    __syncthreads();
#pragma unroll
    for (int p = 0; p < 2; ++p) {
      int row = w * 32 + p * 16;
      GLOAD_LDS16(A + (long long)(m0 + row + lrow) * K + k0 + lk,
                  As + row * 32);
      GLOAD_LDS16(B + (long long)(n0 + row + lrow) * K + k0 + lk,
                  Bs + row * 32);
    }
    __syncthreads();
    bf16x8 af[4], bfr[4];
#pragma unroll
    for (int i = 0; i < 4; ++i) {
      af[i]  = *(const bf16x8*)(As + (mw + i * 16 + fr) * 32 + fq * 8);
      bfr[i] = *(const bf16x8*)(Bs + (nw + i * 16 + fr) * 32 + fq * 8);
    }
#pragma unroll
    for (int i = 0; i < 4; ++i)
#pragma unroll
      for (int j = 0; j < 4; ++j)
        acc[i][j] = __builtin_amdgcn_mfma_f32_16x16x32_bf16(
            af[i], bfr[j], acc[i][j], 0, 0, 0);
  }
#pragma unroll
  for (int i = 0; i < 4; ++i) {
#pragma unroll
    for (int j = 0; j < 4; ++j) {
      int n = n0 + nw + j * 16 + fr;
      float bv = bias[n];
#pragma unroll
      for (int q = 0; q < 4; ++q) {
        int m = m0 + mw + i * 16 + fq * 4 + q;
        if constexpr (BF16OUT)
          ((ushort*)Cv)[(long long)m * N + n] = f2bf(acc[i][j][q] + bv);
        else
          ((float*)Cv)[(long long)m * N + n] = acc[i][j][q] + bv;
      }
    }
  }
}

// ---------------- MFMA rel-shift attention v6 (W ring + packed WbT + DPP) ----
// Delta vs the verified attn5:
//  - W ring: per tile compute only the 64 NEW window cols (g = 1024+64ti-t0+jn)
//    into WbT at ring col c=(64(ti+1)+jn)&127; prologue fills c=0..63
//    (g = 960-t0+j). Score read: c=(64ti+63+delta)&127.
//  - WbT transposed [c][row] -> the 4 q-values pack into one ds_write_b64.
//  - Softmax reductions via DPP row_ror (VALU) instead of shfl (DS pipe).
static __device__ __forceinline__ int kri(int row, int d) {
  return (row * 72 + d) ^ ((row & 8) ? 8 : 0);
}
static __device__ __forceinline__ int vdi(int d, int s) {
  return 64 * 72 + ((d * 72 + s) ^ (((d >> 3) & 7) << 3));
}

__global__ __launch_bounds__(256) void attn6_kernel(
    const ushort* __restrict__ qkv, const ushort* __restrict__ rb,
    const float* __restrict__ rwb, const float* __restrict__ rrb,
    ushort* __restrict__ outb) {
  __shared__ __align__(16) ushort Kls[64 * 72];    // K tile / qw (prologue)
  __shared__ __align__(16) ushort Rls[128 * 72];   // qr / R-new + P | V^T
  __shared__ __align__(16) ushort WbT[128 * 66];   // ring, [c][row 0..64]

  const int t0 = blockIdx.x * 64;
  const int b = blockIdx.y >> 4, h = blockIdx.y & 15;
  const int tid = threadIdx.x;
  const int l = tid & 63, w = tid >> 6;
  const int fr = l & 15, fq = l >> 4;
  const int srow = tid >> 2;        // 0..63
  const int sd0 = (tid & 3) * 16;   // 0,16,32,48

  // ---- prologue A: q+rwb -> Kls; read AC A-frags ----
  {
    long long qo = ((long long)(t0 + srow) * B_SZ + b) * E3 + h * 64 + sd0;
#pragma unroll
    for (int j = 0; j < 16; ++j)
      Kls[kri(srow, sd0 + j)] =
          f2bf(bf2f(qkv[qo + j]) + rwb[h * 64 + sd0 + j]);
  }
  __syncthreads();
  const bf16x8 acA0 = *(const bf16x8*)(Kls + kri(16 * w + fr, fq * 8));
  const bf16x8 acA1 = *(const bf16x8*)(Kls + kri(16 * w + fr, fq * 8 + 32));
  __syncthreads();
  // ---- prologue B: q+rrb rows 0..79 -> Rls; read W A-frags ----
  {
    long long qo = ((long long)(t0 + srow) * B_SZ + b) * E3 + h * 64 + sd0;
#pragma unroll
    for (int j = 0; j < 16; ++j)
      Rls[kri(srow, sd0 + j)] =
          f2bf(bf2f(qkv[qo + j]) + rrb[h * 64 + sd0 + j]);
  }
  if (tid < 64) {
    int row = 64 + (tid >> 2);
    int d0 = (tid & 3) * 16;
    if (row == 64 && t0 + 64 < T_SEQ) {
      long long qo = ((long long)(t0 + 64) * B_SZ + b) * E3 + h * 64 + d0;
#pragma unroll
      for (int j = 0; j < 16; ++j)
        Rls[kri(row, d0 + j)] =
            f2bf(bf2f(qkv[qo + j]) + rrb[h * 64 + d0 + j]);
    } else {
#pragma unroll
      for (int j = 0; j < 16; ++j) Rls[kri(row, d0 + j)] = 0;
    }
  }
  __syncthreads();
  const bf16x8 aW0  = *(const bf16x8*)(Rls + kri(16 * w + fr, fq * 8));
  const bf16x8 aW1  = *(const bf16x8*)(Rls + kri(16 * w + fr, fq * 8 + 32));
  const bf16x8 aW40 = *(const bf16x8*)(Rls + kri(64 + fr, fq * 8));
  const bf16x8 aW41 = *(const bf16x8*)(Rls + kri(64 + fr, fq * 8 + 32));
  __syncthreads();  // frag reads done before R staging overwrites

  // W-phase: 64 cols from Rls rows 0..63 into ring cols (rbase+jn)&127
  auto wphase = [&](int rbase) {
#pragma unroll
    for (int cb = 0; cb < 4; ++cb) {
      bf16x8 r0 = *(const bf16x8*)(Rls + kri(16 * cb + fr, fq * 8));
      bf16x8 r1 = *(const bf16x8*)(Rls + kri(16 * cb + fr, fq * 8 + 32));
      f32x4 acw;
#pragma unroll
      for (int q = 0; q < 4; ++q) acw[q] = 0.f;
      acw = __builtin_amdgcn_mfma_f32_16x16x32_bf16(aW0, r0, acw, 0, 0, 0);
      acw = __builtin_amdgcn_mfma_f32_16x16x32_bf16(aW1, r1, acw, 0, 0, 0);
      ushort4 pk;
      pk.x = f2bf(acw[0]); pk.y = f2bf(acw[1]);
      pk.z = f2bf(acw[2]); pk.w = f2bf(acw[3]);
      int c = (rbase + 16 * cb + fr) & 127;
      *(ushort4*)(WbT + c * 66 + 16 * w + 4 * fq) = pk;
    }
    // row 64 (q[t0+64]); wave w covers new cols 16w..16w+15
    {
      bf16x8 r0 = *(const bf16x8*)(Rls + kri(16 * w + fr, fq * 8));
      bf16x8 r1 = *(const bf16x8*)(Rls + kri(16 * w + fr, fq * 8 + 32));
      f32x4 acw;
#pragma unroll
      for (int q = 0; q < 4; ++q) acw[q] = 0.f;
      acw = __builtin_amdgcn_mfma_f32_16x16x32_bf16(aW40, r0, acw, 0, 0, 0);
      acw = __builtin_amdgcn_mfma_f32_16x16x32_bf16(aW41, r1, acw, 0, 0, 0);
      if (fq == 0) {
        int c = (rbase + 16 * w + fr) & 127;
        WbT[c * 66 + 64] = f2bf(acw[0]);
      }
    }
  };

  // ---- prologue C: stage ring cols 0..63 (g = 960 - t0 + j) and compute ----
  {
    int g = 960 - t0 + srow;  // <= 1023 always
    u16x8 r0, r1;
#pragma unroll
    for (int j = 0; j < 8; ++j) { r0[j] = 0; r1[j] = 0; }
    if (g >= 0) {
      long long ro = (long long)g * E_DIM + h * 64 + sd0;
      r0 = *(const u16x8*)(rb + ro);
      r1 = *(const u16x8*)(rb + ro + 8);
    }
    *(u16x8*)(Rls + kri(srow, sd0)) = r0;
    *(u16x8*)(Rls + kri(srow, sd0 + 8)) = r1;
  }
  __syncthreads();
  wphase(0);
  __syncthreads();  // wphase reads done before tile-0 staging

  float m_r[4], l_r[4];
  f32x4 oacc[4];
#pragma unroll
  for (int q = 0; q < 4; ++q) { m_r[q] = -1e30f; l_r[q] = 0.f; }
#pragma unroll
  for (int c = 0; c < 4; ++c)
#pragma unroll
    for (int q = 0; q < 4; ++q) oacc[c][q] = 0.f;

  for (int ti = 0; ti < 16; ++ti) {
    const int s0 = ti * 64;
    // stage K tile [s][d]
    {
      long long ko =
          ((long long)(s0 + srow) * B_SZ + b) * E3 + E_DIM + h * 64 + sd0;
      u16x8 k0 = *(const u16x8*)(qkv + ko);
      u16x8 k1 = *(const u16x8*)(qkv + ko + 8);
      *(u16x8*)(Kls + kri(srow, sd0)) = k0;
      *(u16x8*)(Kls + kri(srow, sd0 + 8)) = k1;
    }
    // stage 64 NEW R-window rows: g = 1024 + 64ti - t0 + jn  (jn = srow)
    {
      int g = 1024 + 64 * ti - t0 + srow;
      int cr = (g <= 1023) ? g : g - 1025;
      u16x8 r0, r1;
#pragma unroll
      for (int j = 0; j < 8; ++j) { r0[j] = 0; r1[j] = 0; }
      if (cr >= 0 && cr < 1024) {
        long long ro = (long long)cr * E_DIM + h * 64 + sd0;
        r0 = *(const u16x8*)(rb + ro);
        r1 = *(const u16x8*)(rb + ro + 8);
      }
      *(u16x8*)(Rls + kri(srow, sd0)) = r0;
      *(u16x8*)(Rls + kri(srow, sd0 + 8)) = r1;
    }
    __syncthreads();  // B_a

    // AC GEMM
    f32x4 accAC[4];
#pragma unroll
    for (int c = 0; c < 4; ++c)
#pragma unroll
      for (int q = 0; q < 4; ++q) accAC[c][q] = 0.f;
#pragma unroll
    for (int cf = 0; cf < 4; ++cf) {
      bf16x8 b0 = *(const bf16x8*)(Kls + kri(16 * cf + fr, fq * 8));
      bf16x8 b1 = *(const bf16x8*)(Kls + kri(16 * cf + fr, fq * 8 + 32));
      accAC[cf] = __builtin_amdgcn_mfma_f32_16x16x32_bf16(acA0, b0, accAC[cf], 0, 0, 0);
      accAC[cf] = __builtin_amdgcn_mfma_f32_16x16x32_bf16(acA1, b1, accAC[cf], 0, 0, 0);
    }
    // W GEMM: only the 64 new cols, ring base 64(ti+1)
    wphase(64 * (ti + 1));
    __syncthreads();  // B_b

    // assemble scores + online softmax (DPP reductions)
    const int thr = t0 - s0;
    float pvv[4][4];
#pragma unroll
    for (int q = 0; q < 4; ++q) {
      const int dt_ = 16 * w + 4 * fq + q;
      float sc[4];
#pragma unroll
      for (int cf = 0; cf < 4; ++cf) {
        const int delta = 16 * cf + fr - dt_;
        const int sel = (delta > thr) ? 1 : 0;
        const int c = (64 * ti + 63 + delta) & 127;
        float Wv = (delta == thr + 1) ? 0.f : bf2f(WbT[c * 66 + dt_ + sel]);
        sc[cf] = (accAC[cf][q] + Wv) * 0.125f;
      }
      float mt = fmaxf(fmaxf(sc[0], sc[1]), fmaxf(sc[2], sc[3]));
      mt = row16_max(mt);
      float mnew = fmaxf(m_r[q], mt);
      float alpha = __expf(m_r[q] - mnew);
      m_r[q] = mnew;
      float ps = 0.f;
#pragma unroll
      for (int cf = 0; cf < 4; ++cf) {
        pvv[q][cf] = __expf(sc[cf] - mnew);
        ps += pvv[q][cf];
      }
      ps = row16_sum(ps);
      l_r[q] = l_r[q] * alpha + ps;
#pragma unroll
      for (int cfd = 0; cfd < 4; ++cfd) oacc[cfd][q] *= alpha;
    }
    // write P [t][s] into Rls rows 0..63; V^T [d][s] into Rls rows 64..127
#pragma unroll
    for (int q = 0; q < 4; ++q)
#pragma unroll
      for (int cf = 0; cf < 4; ++cf)
        Rls[kri(16 * w + 4 * fq + q, 16 * cf + fr)] = f2bf(pvv[q][cf]);
    {
      long long vo =
          ((long long)(s0 + srow) * B_SZ + b) * E3 + 2 * E_DIM + h * 64 + sd0;
      u16x8 v0 = *(const u16x8*)(qkv + vo);
      u16x8 v1 = *(const u16x8*)(qkv + vo + 8);
#pragma unroll
      for (int j = 0; j < 8; ++j) {
        Rls[vdi(sd0 + j, srow)] = (ushort)v0[j];
        Rls[vdi(sd0 + 8 + j, srow)] = (ushort)v1[j];
      }
    }
    __syncthreads();  // B_c

    // PV GEMM
#pragma unroll
    for (int ks = 0; ks < 2; ++ks) {
      bf16x8 aP = *(const bf16x8*)(Rls + kri(16 * w + fr, fq * 8 + 32 * ks));
#pragma unroll
      for (int cfd = 0; cfd < 4; ++cfd) {
        bf16x8 bV = *(const bf16x8*)(Rls + vdi(16 * cfd + fr, fq * 8 + 32 * ks));
        oacc[cfd] =
            __builtin_amdgcn_mfma_f32_16x16x32_bf16(aP, bV, oacc[cfd], 0, 0, 0);
      }
    }
    __syncthreads();  // B_d: PV reads done before next tile's staging
  }

#pragma unroll
  for (int q = 0; q < 4; ++q) {
    float inv = 1.f / l_r[q];
    int t = t0 + 16 * w + 4 * fq + q;
#pragma unroll
    for (int cfd = 0; cfd < 4; ++cfd)
      outb[((long long)t * B_SZ + b) * E_DIM + h * 64 + 16 * cfd + fr] =
          f2bf(oacc[cfd][q] * inv);
  }
}

// ---------------- launch ----------------
extern "C" void kernel_launch(void* const* d_in, const int* in_sizes, int n_in,
                              void* d_out, int out_size, void* d_ws,
                              size_t ws_size, hipStream_t stream) {
  const float* input = (const float*)d_in[0];
  const float* pos   = (const float*)d_in[1];
  const int*   idx   = (const int*)d_in[2];
  const float* in_w  = (const float*)d_in[3];
  const float* in_b  = (const float*)d_in[4];
  const float* out_w = (const float*)d_in[5];
  const float* out_b = (const float*)d_in[6];
  const float* pos_w = (const float*)d_in[7];
  const float* pos_b = (const float*)d_in[8];
  const float* r_i   = (const float*)d_in[9];
  const float* s_i   = (const float*)d_in[10];
  const float* r_p   = (const float*)d_in[11];
  const float* s_p   = (const float*)d_in[12];
  const float* r_o   = (const float*)d_in[13];
  const float* s_o   = (const float*)d_in[14];
  const float* rm_i  = (const float*)d_in[15];
  const float* sm_i  = (const float*)d_in[16];
  const float* rm_p  = (const float*)d_in[17];
  const float* sm_p  = (const float*)d_in[18];
  const float* rm_o  = (const float*)d_in[19];
  const float* sm_o  = (const float*)d_in[20];
  const float* rwb   = (const float*)d_in[21];
  const float* rrb   = (const float*)d_in[22];
  float* out = (float*)d_out;

  // workspace layout (bytes), ~46 MB total
  char* base = (char*)d_ws;
  ushort* qkvb  = (ushort*)(base);                        // 24MB bf16 [4096][3072]
  ushort* rbufb = (ushort*)(base + 24ll * 1024 * 1024);   //  2MB bf16 [1024][1024]
  ushort* Wi    = (ushort*)(base + 26ll * 1024 * 1024);   //  6MB
  ushort* Wp    = (ushort*)(base + 32ll * 1024 * 1024);   //  2MB
  ushort* Wo    = (ushort*)(base + 34ll * 1024 * 1024);   //  2MB
  ushort* ibf   = (ushort*)(base + 36ll * 1024 * 1024);   //  8MB bf16 [4096][1024]
  ushort* pbf   = (ushort*)(base + 44ll * 1024 * 1024);   //  2MB
  ushort* abf   = ibf;  // attn out aliases ibf (dead after qkv GEMM)

  cast_bf16_kernel<<<(T_SEQ * B_SZ * E_DIM / 4 + 255) / 256, 256, 0, stream>>>(
      input, ibf, (long long)T_SEQ * B_SZ * E_DIM / 4);
  cast_bf16_kernel<<<(T_SEQ * E_DIM / 4 + 255) / 256, 256, 0, stream>>>(
      pos, pbf, (long long)T_SEQ * E_DIM / 4);
  {
    long long n1 = (long long)E3 * E_DIM;
    factorize_kernel<<<(n1 + 255) / 256, 256, 0, stream>>>(
        in_w, rm_i, sm_i, r_i, s_i, idx, Wi, E3, E_DIM);
    long long n2 = (long long)E_DIM * E_DIM;
    factorize_kernel<<<(n2 + 255) / 256, 256, 0, stream>>>(
        pos_w, rm_p, sm_p, r_p, s_p, idx, Wp, E_DIM, E_DIM);
    factorize_kernel<<<(n2 + 255) / 256, 256, 0, stream>>>(
        out_w, rm_o, sm_o, r_o, s_o, idx, Wo, E_DIM, E_DIM);
  }
  // qkv (bf16) = input @ Wi^T + bias
  gemm_mfma_kernel<true><<<dim3(E3 / 128, (T_SEQ * B_SZ) / 128), 256, 0, stream>>>(
      ibf, Wi, in_b, qkvb, T_SEQ * B_SZ, E3, E_DIM);
  // rbuf (bf16) = pos @ Wp^T + bias
  gemm_mfma_kernel<true><<<dim3(E_DIM / 128, T_SEQ / 128), 256, 0, stream>>>(
      pbf, Wp, pos_b, rbufb, T_SEQ, E_DIM, E_DIM);
  // fused MFMA attention -> abf (bf16)
  attn6_kernel<<<dim3(T_SEQ / 64, B_SZ * H_DIM), 256, 0, stream>>>(
      qkvb, rbufb, rwb, rrb, abf);
  // out (f32) = attn @ Wo^T + bias
  gemm_mfma_kernel<false><<<dim3(E_DIM / 128, (T_SEQ * B_SZ) / 128), 256, 0, stream>>>(
      abf, Wo, out_b, out, T_SEQ * B_SZ, E_DIM, E_DIM);
}